// Round 11
// baseline (266.624 us; speedup 1.0000x reference)
//
#include <hip/hip_runtime.h>
#include <hip/hip_bf16.h>

using bf16 = __hip_bfloat16;
typedef __attribute__((ext_vector_type(8))) short bf16x8;   // 8 bf16 = 4 VGPR
typedef __attribute__((ext_vector_type(4))) float f32x4;    // MFMA C/D frag

#define DEVI __device__ __forceinline__

constexpr int Bn = 2, Sn = 2048, Dn = 2048, Hn = 16, DHn = 128;
constexpr int Mn = Bn * Sn;   // 4096

DEVI void gload_lds16(const bf16* g, bf16* l) {
  __builtin_amdgcn_global_load_lds(
      (__attribute__((address_space(1))) void*)g,
      (__attribute__((address_space(3))) void*)l,
      16, 0, 0);
}

// ---------------- fused f32 -> bf16 convert (x + 4 weights, one launch) ----
__global__ __launch_bounds__(256) void cvt_all_k(const float* __restrict__ x,
                                                 const float* __restrict__ wq,
                                                 const float* __restrict__ wk,
                                                 const float* __restrict__ wv,
                                                 const float* __restrict__ wo,
                                                 bf16* __restrict__ xb,
                                                 bf16* __restrict__ wb) {
  const int which = blockIdx.y;
  const float* src;
  bf16* dst;
  int n8;
  if (which == 0) { src = x;  dst = xb; n8 = Mn * Dn / 8; }
  else {
    src = (which == 1) ? wq : (which == 2) ? wk : (which == 3) ? wv : wo;
    dst = wb + (size_t)(which - 1) * Dn * Dn;
    n8 = Dn * Dn / 8;
  }
  for (int i = blockIdx.x * 256 + threadIdx.x; i < n8; i += gridDim.x * 256) {
    const float4* p = (const float4*)src + (size_t)i * 2;
    float4 a = p[0], b = p[1];
    union { bf16 h[8]; bf16x8 v; } u;
    u.h[0] = __float2bfloat16(a.x); u.h[1] = __float2bfloat16(a.y);
    u.h[2] = __float2bfloat16(a.z); u.h[3] = __float2bfloat16(a.w);
    u.h[4] = __float2bfloat16(b.x); u.h[5] = __float2bfloat16(b.y);
    u.h[6] = __float2bfloat16(b.z); u.h[7] = __float2bfloat16(b.w);
    *((bf16x8*)dst + i) = u.v;
  }
}

// ---------------- GEMM Y: C = A[M,K-slice] * W[N,K-slice]^T ----------------
// BM=256, BN=128, BK=32, 256 thr = 4 waves (2M x 2N), per-wave C = 128x64.
// 2-slot LDS ring (48 KB -> 2 blocks/CU), counted vmcnt, phase-spread
// staging, T2 swizzle, T5 setprio. Ledger: tile kt's A0,A2,B0,B1 @ kt-2 ph1;
// A1,A3 @ kt-1 ph0; tile-top vmcnt(4) retires tile kt (last tile vmcnt(0)).
// MODE 0: bf16 out, z-slab from column tile (fused QKV).
// MODE 1: f32 PARTIAL out, split-K via blockIdx.z (kbase = z*NTK*32), each z
//         writes its own Mn x 2048 f32 slab (summed by reduce_k).
template <int MODE, int NTOT, int NMAT, int NTK>
__global__ __launch_bounds__(256, 2) void gemmY(const bf16* __restrict__ A,
                                                const bf16* __restrict__ W,
                                                void* __restrict__ Cv) {
  constexpr int K = 2048;
  __shared__ bf16 smem[2 * 12288];   // 48 KB: per slot A[256][32] + B[128][32]

  const int nwg = NTOT * 16;
  const int orig = blockIdx.x;
  const int wgid = (orig & 7) * (nwg >> 3) + (orig >> 3);   // XCD swizzle (nwg%8==0)
  const int bm = wgid / NTOT;
  const int bnn = wgid % NTOT;
  constexpr int nper = NTOT / NMAT;
  const int z = bnn / nper;
  const int col0 = (bnn % nper) * 128;
  const int kbase = (MODE == 1) ? (int)blockIdx.z * (NTK * 32) : 0;

  const int t = threadIdx.x;
  const int wave = t >> 6, lane = t & 63;
  const int wm = wave >> 1, wn = wave & 1;
  const int lr = lane & 15, lg = lane >> 4;
  const int rch = ((lg ^ ((lr >> 1) & 3)) * 8);       // swizzled read chunk
  const int srow = t >> 2;                            // staging row in unit
  const int sch = (t & 3) ^ ((t >> 3) & 3);           // pre-swizzled src chunk

  const bf16* Ab = A + (size_t)(bm * 256 + srow) * K + kbase + sch * 8;
  const bf16* Bb = W + (size_t)z * (2048 * 2048) +
                   (size_t)(col0 + srow) * K + kbase + sch * 8;

  auto stgA = [&](int slot, int kt, int u) {
    gload_lds16(Ab + (size_t)u * 64 * K + kt * 32,
                smem + slot * 12288 + u * 2048 + t * 8);
  };
  auto stgB = [&](int slot, int kt, int v) {
    gload_lds16(Bb + (size_t)v * 64 * K + kt * 32,
                smem + slot * 12288 + 8192 + v * 2048 + t * 8);
  };

  f32x4 acc[8][4];
  const f32x4 zf = {0.f, 0.f, 0.f, 0.f};
#pragma unroll
  for (int i = 0; i < 8; ++i)
#pragma unroll
    for (int j = 0; j < 4; ++j) acc[i][j] = zf;

  // prologue: tile0 complete (6 units), tile1 partial (A0,A2,B0,B1)
  stgA(0, 0, 0); stgA(0, 0, 1); stgA(0, 0, 2); stgA(0, 0, 3);
  stgB(0, 0, 0); stgB(0, 0, 1);
  stgA(1, 1, 0); stgA(1, 1, 2); stgB(1, 1, 0); stgB(1, 1, 1);

#pragma unroll 2
  for (int kt = 0; kt < NTK; ++kt) {
    const int slot = kt & 1;
    const bf16* sAb = smem + slot * 12288;
    const bf16* sBb = sAb + 8192;

    // ---- tile top: guarantee slot kt fully landed, publish to all waves ----
    if (kt == NTK - 1) asm volatile("s_waitcnt vmcnt(0)" ::: "memory");
    else               asm volatile("s_waitcnt vmcnt(4)" ::: "memory");
    __builtin_amdgcn_s_barrier();

    // ---- phase 0: af(mh=0) + bv(all); stage kt+1's A1,A3 ----
    bf16x8 af[4], bv[4];
#pragma unroll
    for (int i = 0; i < 4; ++i)
      af[i] = *(const bf16x8*)(sAb + (wm * 128 + i * 16 + lr) * 32 + rch);
#pragma unroll
    for (int n = 0; n < 4; ++n)
      bv[n] = *(const bf16x8*)(sBb + (wn * 64 + n * 16 + lr) * 32 + rch);
    if (kt + 1 < NTK) { stgA(slot ^ 1, kt + 1, 1); stgA(slot ^ 1, kt + 1, 3); }
    asm volatile("s_waitcnt lgkmcnt(0)" ::: "memory");
    __builtin_amdgcn_sched_barrier(0);      // rule 18
    __builtin_amdgcn_s_setprio(1);
#pragma unroll
    for (int i = 0; i < 4; ++i)
#pragma unroll
      for (int n = 0; n < 4; ++n)
        acc[i][n] = __builtin_amdgcn_mfma_f32_16x16x32_bf16(af[i], bv[n], acc[i][n], 0, 0, 0);
    __builtin_amdgcn_s_setprio(0);
    __builtin_amdgcn_s_barrier();           // A0,A2,B0,B1 of slot kt now dead

    // ---- phase 1: af(mh=1); stage kt+2's A0,A2,B0,B1 into freed regions ----
#pragma unroll
    for (int i = 0; i < 4; ++i)
      af[i] = *(const bf16x8*)(sAb + (wm * 128 + 64 + i * 16 + lr) * 32 + rch);
    if (kt + 2 < NTK) {
      stgA(slot, kt + 2, 0); stgA(slot, kt + 2, 2);
      stgB(slot, kt + 2, 0); stgB(slot, kt + 2, 1);
    }
    asm volatile("s_waitcnt lgkmcnt(0)" ::: "memory");
    __builtin_amdgcn_sched_barrier(0);
    __builtin_amdgcn_s_setprio(1);
#pragma unroll
    for (int i = 0; i < 4; ++i)
#pragma unroll
      for (int n = 0; n < 4; ++n)
        acc[4 + i][n] = __builtin_amdgcn_mfma_f32_16x16x32_bf16(af[i], bv[n], acc[4 + i][n], 0, 0, 0);
    __builtin_amdgcn_s_setprio(0);
    // next tile-top barrier closes this phase.
  }

  // epilogue
  const int r0 = bm * 256 + wm * 128, c0 = col0 + wn * 64;
#pragma unroll
  for (int mm = 0; mm < 8; ++mm)
#pragma unroll
    for (int nn = 0; nn < 4; ++nn) {
      const int rr = r0 + mm * 16 + lg * 4;
      const int cc = c0 + nn * 16 + lr;
#pragma unroll
      for (int r = 0; r < 4; ++r) {
        float v = acc[mm][nn][r];
        if (MODE == 1) {
          float* P = (float*)Cv + (size_t)blockIdx.z * (Mn * 2048);
          P[(size_t)(rr + r) * 2048 + cc] = v;
        } else {
          bf16* C = (bf16*)Cv + (size_t)z * (Mn * 2048);
          C[(size_t)(rr + r) * 2048 + cc] = __float2bfloat16(v);
        }
      }
    }
}

// ---------------- split-K reduce: out = P0 + P1 (f32) ----------------------
__global__ __launch_bounds__(256) void reduce_k(const float* __restrict__ P,
                                                float* __restrict__ out, int n4) {
  const float4* P0 = (const float4*)P;
  const float4* P1 = (const float4*)(P + (size_t)Mn * 2048);
  float4* O = (float4*)out;
  for (int i = blockIdx.x * 256 + threadIdx.x; i < n4; i += gridDim.x * 256) {
    float4 a = P0[i], b = P1[i];
    O[i] = make_float4(a.x + b.x, a.y + b.y, a.z + b.z, a.w + b.w);
  }
}

// ---------------- V transpose: per (b,h)  V[2048,128] -> VT[128,2048] ------
__global__ __launch_bounds__(256, 2) void transpose_v(const bf16* __restrict__ V,
                                                      bf16* __restrict__ VT) {
  __shared__ bf16 tile[128 * 128];   // 32 KB, chunk-XOR-swizzled
  const int kt = blockIdx.x, bh = blockIdx.y;
  const bf16* Vh = V + (size_t)bh * (Sn * DHn);
  bf16* VTh = VT + (size_t)bh * (DHn * Sn);
  const int t = threadIdx.x;
  const int rr = t >> 4, cc = t & 15;
#pragma unroll
  for (int i = 0; i < 8; ++i) {
    int r = rr + i * 16;
    int ch = cc ^ ((r >> 3) & 7);
    *(bf16x8*)(tile + r * 128 + ch * 8) =
        *(const bf16x8*)(Vh + (size_t)(kt * 128 + r) * DHn + cc * 8);
  }
  __syncthreads();
  const int dr = t >> 4, li = t & 15;
#pragma unroll
  for (int i = 0; i < 8; ++i) {
    int dh = dr + i * 16;
    union { bf16 h[8]; bf16x8 v; } u;
#pragma unroll
    for (int j = 0; j < 8; ++j) {
      int k = li * 8 + j;
      int ch = (dh >> 3) ^ ((k >> 3) & 7);
      u.h[j] = tile[k * 128 + ch * 8 + (dh & 7)];
    }
    *(bf16x8*)(VTh + (size_t)dh * Sn + kt * 128 + li * 8) = u.v;
  }
}

// ---------------- causal flash attention v3 --------------------------------
// QBLK=128, 8 waves x 16 q-rows, KBLK=64. Block pairs qb=j with qb=15-j
// (34 tiles each; 256 blocks = 1/CU). XCD-grouped grid decode.
__global__ __launch_bounds__(512, 1) void attn_k3(const bf16* __restrict__ Q,
                                                  const bf16* __restrict__ K,
                                                  const bf16* __restrict__ VT,
                                                  bf16* __restrict__ Mg) {
  __shared__ bf16 smem[40960];         // 80 KB
  bf16* sK0 = smem;
  bf16* sK1 = smem + 8192;
  bf16* sV0 = smem + 16384;
  bf16* sV1 = smem + 24576;
  bf16* sP  = smem + 32768;
  bf16* sO  = smem;

  const int bi = blockIdx.x;
  const int xcd = bi & 7, slt = bi >> 3;
  const int bh = (slt & 3) * 8 + xcd;
  const int j = slt >> 2;
  const bf16* Qh = Q + (size_t)bh * (Sn * DHn);
  const bf16* Kh = K + (size_t)bh * (Sn * DHn);
  const bf16* VTh = VT + (size_t)bh * (DHn * Sn);
  const int b = bh >> 4, h = bh & 15;

  const int t = threadIdx.x, wave = t >> 6, lane = t & 63;
  const int lr = lane & 15, lg = lane >> 4;

  auto STAGE = [&](int buf, int kt) {
    bf16* dK = buf ? sK1 : sK0;
    bf16* dV = buf ? sV1 : sV0;
#pragma unroll
    for (int i = 0; i < 2; ++i) {
      int c = i * 512 + t;
      int row = c >> 4, c16 = c & 15;
      gload_lds16(Kh + (size_t)(kt * 64 + row) * DHn + ((c16 ^ (row & 7)) * 8),
                  dK + c * 8);
    }
#pragma unroll
    for (int i = 0; i < 2; ++i) {
      int c = i * 512 + t;
      int row = c >> 3, c8 = c & 7;
      gload_lds16(VTh + (size_t)row * Sn + kt * 64 + ((c8 ^ (row & 7)) * 8),
                  dV + c * 8);
    }
  };

  const f32x4 zf = {0.f, 0.f, 0.f, 0.f};

  for (int pi = 0; pi < 2; ++pi) {
    const int qb = pi ? (15 - j) : j;
    const int nt = qb * 2 + 2;
    const int q0 = qb * 128 + wave * 16;

    bf16x8 qf[4];
#pragma unroll
    for (int kk = 0; kk < 4; ++kk)
      qf[kk] = *(const bf16x8*)(Qh + (size_t)(q0 + lr) * DHn + kk * 32 + lg * 8);

    f32x4 o[8];
#pragma unroll
    for (int d = 0; d < 8; ++d) o[d] = zf;
    float mrun[4], lrun[4];
#pragma unroll
    for (int r = 0; r < 4; ++r) { mrun[r] = -3e38f; lrun[r] = 0.f; }

    STAGE(0, 0);
    __syncthreads();
    int cur = 0;

    for (int kt = 0; kt < nt; ++kt) {
      if (kt + 1 < nt) STAGE(cur ^ 1, kt + 1);

      bf16* sKc = cur ? sK1 : sK0;
      bf16* sVc = cur ? sV1 : sV0;

      f32x4 sfr[4];
#pragma unroll
      for (int nn = 0; nn < 4; ++nn) sfr[nn] = zf;
#pragma unroll
      for (int kk = 0; kk < 4; ++kk)
#pragma unroll
        for (int nn = 0; nn < 4; ++nn) {
          int row = nn * 16 + lr;
          int ch = (kk * 4 + lg) ^ (row & 7);
          bf16x8 kf = *(const bf16x8*)(sKc + row * DHn + ch * 8);
          sfr[nn] = __builtin_amdgcn_mfma_f32_16x16x32_bf16(qf[kk], kf, sfr[nn], 0, 0, 0);
        }

      const bool maskt = (kt >= qb * 2);
      float pv[4][4];
#pragma unroll
      for (int nn = 0; nn < 4; ++nn)
#pragma unroll
        for (int r = 0; r < 4; ++r) {
          float v = sfr[nn][r] * (1.0f / 128.0f);
          if (maskt) {
            int kg = kt * 64 + nn * 16 + lr;
            int qg = q0 + lg * 4 + r;
            if (kg > qg) v = -1e30f;
          }
          pv[nn][r] = v;
        }
      float mnew[4], alpha[4], rsum[4];
#pragma unroll
      for (int r = 0; r < 4; ++r) {
        float rm = fmaxf(fmaxf(pv[0][r], pv[1][r]), fmaxf(pv[2][r], pv[3][r]));
        rm = fmaxf(rm, __shfl_xor(rm, 1));
        rm = fmaxf(rm, __shfl_xor(rm, 2));
        rm = fmaxf(rm, __shfl_xor(rm, 4));
        rm = fmaxf(rm, __shfl_xor(rm, 8));
        mnew[r] = fmaxf(mrun[r], rm);
        alpha[r] = __expf(mrun[r] - mnew[r]);
        mrun[r] = mnew[r];
        rsum[r] = 0.f;
      }
#pragma unroll
      for (int nn = 0; nn < 4; ++nn)
#pragma unroll
        for (int r = 0; r < 4; ++r) {
          float p = __expf(pv[nn][r] - mnew[r]);
          pv[nn][r] = p;
          rsum[r] += p;
        }
#pragma unroll
      for (int r = 0; r < 4; ++r) {
        float s = rsum[r];
        s += __shfl_xor(s, 1); s += __shfl_xor(s, 2);
        s += __shfl_xor(s, 4); s += __shfl_xor(s, 8);
        lrun[r] = lrun[r] * alpha[r] + s;
      }
#pragma unroll
      for (int d = 0; d < 8; ++d)
#pragma unroll
        for (int r = 0; r < 4; ++r) o[d][r] *= alpha[r];

#pragma unroll
      for (int nn = 0; nn < 4; ++nn)
#pragma unroll
        for (int r = 0; r < 4; ++r) {
          int row = lg * 4 + r;
          int chk = (nn * 2 + (lr >> 3)) ^ (row & 7);
          sP[wave * 1024 + row * 64 + chk * 8 + (lr & 7)] = __float2bfloat16(pv[nn][r]);
        }

      bf16x8 pf[2];
#pragma unroll
      for (int kk = 0; kk < 2; ++kk) {
        int ch = (kk * 4 + lg) ^ (lr & 7);
        pf[kk] = *(const bf16x8*)(sP + wave * 1024 + lr * 64 + ch * 8);
      }
#pragma unroll
      for (int d = 0; d < 8; ++d)
#pragma unroll
        for (int kk = 0; kk < 2; ++kk) {
          int vrow = d * 16 + lr;
          int vch = (kk * 4 + lg) ^ (vrow & 7);
          bf16x8 vf = *(const bf16x8*)(sVc + vrow * 64 + vch * 8);
          o[d] = __builtin_amdgcn_mfma_f32_16x16x32_bf16(pf[kk], vf, o[d], 0, 0, 0);
        }

      __syncthreads();
      cur ^= 1;
    }

    float inv[4];
#pragma unroll
    for (int r = 0; r < 4; ++r) inv[r] = 1.0f / lrun[r];
#pragma unroll
    for (int d = 0; d < 8; ++d)
#pragma unroll
      for (int r = 0; r < 4; ++r) {
        int row = wave * 16 + lg * 4 + r;
        int col = d * 16 + lr;
        int chk = ((col >> 3) ^ (row & 7));
        sO[row * 128 + chk * 8 + (col & 7)] = __float2bfloat16(o[d][r] * inv[r]);
      }
    __syncthreads();
    bf16* Mh = Mg + ((size_t)(b * Sn + qb * 128)) * Dn + h * DHn;
#pragma unroll
    for (int i = 0; i < 4; ++i) {
      int row = (t >> 4) + i * 32;
      int c16 = t & 15;
      *(bf16x8*)(Mh + (size_t)row * Dn + c16 * 8) =
          *(const bf16x8*)(sO + row * 128 + ((c16 ^ (row & 7)) * 8));
    }
    __syncthreads();
  }
}

// ---------------------------------------------------------------------------
extern "C" void kernel_launch(void* const* d_in, const int* in_sizes, int n_in,
                              void* d_out, int out_size, void* d_ws, size_t ws_size,
                              hipStream_t stream) {
  const float* x = (const float*)d_in[0];
  const float* Wq = (const float*)d_in[1];
  const float* Wk = (const float*)d_in[2];
  const float* Wv = (const float*)d_in[3];
  const float* Wo = (const float*)d_in[4];
  float* out = (float*)d_out;

  char* ws = (char*)d_ws;
  bf16* xb = (bf16*)ws;            ws += (size_t)Mn * Dn * 2;        // 16 MB
  bf16* Wb = (bf16*)ws;            ws += (size_t)4 * Dn * Dn * 2;    // 32 MB (q,k,v,o)
  bf16* QKV = (bf16*)ws;           ws += (size_t)3 * Mn * Dn * 2;    // 48 MB
  bf16* VT = (bf16*)ws;            ws += (size_t)Bn * Hn * DHn * Sn * 2; // 16 MB
  bf16* Mg = (bf16*)ws;            ws += (size_t)Mn * Dn * 2;        // 16 MB
  // split-K partials (2 x 32 MB f32) reuse QKV+VT (dead after attention)
  float* Pk = (float*)QKV;

  // all f32->bf16 conversions in one launch
  cvt_all_k<<<dim3(2048, 5), 256, 0, stream>>>(x, Wq, Wk, Wv, Wo, xb, Wb);

  // Q,K,V = x @ W{q,k,v}^T -> bf16 (768 blocks, BM=256, full K)
  gemmY<0, 48, 3, 64><<<768, 256, 0, stream>>>(xb, Wb, (void*)QKV);

  // per-head V transpose (plain-view head slabs)
  transpose_v<<<dim3(16, 32), 256, 0, stream>>>(QKV + 2 * (size_t)Mn * Dn, VT);

  // causal attention -> merged [4096, 2048] bf16 (XCD-grouped grid)
  attn_k3<<<256, 512, 0, stream>>>(QKV, QKV + (size_t)Mn * Dn, VT, Mg);

  // out-proj: split-K=2 -> f32 partials (512 blocks = 2/CU), then reduce
  gemmY<1, 16, 1, 32><<<dim3(256, 1, 2), 256, 0, stream>>>(Mg, Wb + 3 * (size_t)Dn * Dn, (void*)Pk);
  reduce_k<<<2048, 256, 0, stream>>>(Pk, out, Mn * Dn / 4);
}

// Round 12
// 251.326 us; speedup vs baseline: 1.0609x; 1.0609x over previous
//
#include <hip/hip_runtime.h>
#include <hip/hip_bf16.h>

using bf16 = __hip_bfloat16;
typedef __attribute__((ext_vector_type(8))) short bf16x8;   // 8 bf16 = 4 VGPR
typedef __attribute__((ext_vector_type(4))) float f32x4;    // MFMA C/D frag

#define DEVI __device__ __forceinline__

constexpr int Bn = 2, Sn = 2048, Dn = 2048, Hn = 16, DHn = 128;
constexpr int Mn = Bn * Sn;   // 4096

DEVI void gload_lds16(const bf16* g, bf16* l) {
  __builtin_amdgcn_global_load_lds(
      (__attribute__((address_space(1))) void*)g,
      (__attribute__((address_space(3))) void*)l,
      16, 0, 0);
}

// ---------------- fused f32 -> bf16 convert (x + 4 weights, one launch) ----
__global__ __launch_bounds__(256) void cvt_all_k(const float* __restrict__ x,
                                                 const float* __restrict__ wq,
                                                 const float* __restrict__ wk,
                                                 const float* __restrict__ wv,
                                                 const float* __restrict__ wo,
                                                 bf16* __restrict__ xb,
                                                 bf16* __restrict__ wb) {
  const int which = blockIdx.y;
  const float* src;
  bf16* dst;
  int n8;
  if (which == 0) { src = x;  dst = xb; n8 = Mn * Dn / 8; }
  else {
    src = (which == 1) ? wq : (which == 2) ? wk : (which == 3) ? wv : wo;
    dst = wb + (size_t)(which - 1) * Dn * Dn;
    n8 = Dn * Dn / 8;
  }
  for (int i = blockIdx.x * 256 + threadIdx.x; i < n8; i += gridDim.x * 256) {
    const float4* p = (const float4*)src + (size_t)i * 2;
    float4 a = p[0], b = p[1];
    union { bf16 h[8]; bf16x8 v; } u;
    u.h[0] = __float2bfloat16(a.x); u.h[1] = __float2bfloat16(a.y);
    u.h[2] = __float2bfloat16(a.z); u.h[3] = __float2bfloat16(a.w);
    u.h[4] = __float2bfloat16(b.x); u.h[5] = __float2bfloat16(b.y);
    u.h[6] = __float2bfloat16(b.z); u.h[7] = __float2bfloat16(b.w);
    *((bf16x8*)dst + i) = u.v;
  }
}

// ---------------- GEMM Y (QKV): C = A[M,K] * W[N,K]^T ----------------------
// BM=256, BN=128, BK=32, 256 thr = 4 waves (2M x 2N), per-wave C = 128x64.
// 2-slot LDS ring (48 KB -> 2 blocks/CU), counted vmcnt, phase-spread
// staging, T2 swizzle, T5 setprio. Ledger: tile kt's A0,A2,B0,B1 @ kt-2 ph1;
// A1,A3 @ kt-1 ph0; tile-top vmcnt(4) retires tile kt (last tile vmcnt(0)).
template <int NTOT, int NMAT>
__global__ __launch_bounds__(256, 2) void gemmY(const bf16* __restrict__ A,
                                                const bf16* __restrict__ W,
                                                bf16* __restrict__ Cv) {
  constexpr int K = 2048, NT = 64;
  __shared__ bf16 smem[2 * 12288];   // 48 KB: per slot A[256][32] + B[128][32]

  const int nwg = NTOT * 16;
  const int orig = blockIdx.x;
  const int wgid = (orig & 7) * (nwg >> 3) + (orig >> 3);   // XCD swizzle (nwg%8==0)
  const int bm = wgid / NTOT;
  const int bnn = wgid % NTOT;
  constexpr int nper = NTOT / NMAT;
  const int z = bnn / nper;
  const int col0 = (bnn % nper) * 128;

  const int t = threadIdx.x;
  const int wave = t >> 6, lane = t & 63;
  const int wm = wave >> 1, wn = wave & 1;
  const int lr = lane & 15, lg = lane >> 4;
  const int rch = ((lg ^ ((lr >> 1) & 3)) * 8);       // swizzled read chunk
  const int srow = t >> 2;                            // staging row in unit
  const int sch = (t & 3) ^ ((t >> 3) & 3);           // pre-swizzled src chunk

  const bf16* Ab = A + (size_t)(bm * 256 + srow) * K + sch * 8;
  const bf16* Bb = W + (size_t)z * (2048 * 2048) +
                   (size_t)(col0 + srow) * K + sch * 8;

  auto stgA = [&](int slot, int kt, int u) {
    gload_lds16(Ab + (size_t)u * 64 * K + kt * 32,
                smem + slot * 12288 + u * 2048 + t * 8);
  };
  auto stgB = [&](int slot, int kt, int v) {
    gload_lds16(Bb + (size_t)v * 64 * K + kt * 32,
                smem + slot * 12288 + 8192 + v * 2048 + t * 8);
  };

  f32x4 acc[8][4];
  const f32x4 zf = {0.f, 0.f, 0.f, 0.f};
#pragma unroll
  for (int i = 0; i < 8; ++i)
#pragma unroll
    for (int j = 0; j < 4; ++j) acc[i][j] = zf;

  // prologue: tile0 complete (6 units), tile1 partial (A0,A2,B0,B1)
  stgA(0, 0, 0); stgA(0, 0, 1); stgA(0, 0, 2); stgA(0, 0, 3);
  stgB(0, 0, 0); stgB(0, 0, 1);
  stgA(1, 1, 0); stgA(1, 1, 2); stgB(1, 1, 0); stgB(1, 1, 1);

#pragma unroll 2
  for (int kt = 0; kt < NT; ++kt) {
    const int slot = kt & 1;
    const bf16* sAb = smem + slot * 12288;
    const bf16* sBb = sAb + 8192;

    // ---- tile top: guarantee slot kt fully landed, publish to all waves ----
    if (kt == NT - 1) asm volatile("s_waitcnt vmcnt(0)" ::: "memory");
    else              asm volatile("s_waitcnt vmcnt(4)" ::: "memory");
    __builtin_amdgcn_s_barrier();

    // ---- phase 0: af(mh=0) + bv(all); stage kt+1's A1,A3 ----
    bf16x8 af[4], bv[4];
#pragma unroll
    for (int i = 0; i < 4; ++i)
      af[i] = *(const bf16x8*)(sAb + (wm * 128 + i * 16 + lr) * 32 + rch);
#pragma unroll
    for (int n = 0; n < 4; ++n)
      bv[n] = *(const bf16x8*)(sBb + (wn * 64 + n * 16 + lr) * 32 + rch);
    if (kt + 1 < NT) { stgA(slot ^ 1, kt + 1, 1); stgA(slot ^ 1, kt + 1, 3); }
    asm volatile("s_waitcnt lgkmcnt(0)" ::: "memory");
    __builtin_amdgcn_sched_barrier(0);      // rule 18
    __builtin_amdgcn_s_setprio(1);
#pragma unroll
    for (int i = 0; i < 4; ++i)
#pragma unroll
      for (int n = 0; n < 4; ++n)
        acc[i][n] = __builtin_amdgcn_mfma_f32_16x16x32_bf16(af[i], bv[n], acc[i][n], 0, 0, 0);
    __builtin_amdgcn_s_setprio(0);
    __builtin_amdgcn_s_barrier();           // A0,A2,B0,B1 of slot kt now dead

    // ---- phase 1: af(mh=1); stage kt+2's A0,A2,B0,B1 into freed regions ----
#pragma unroll
    for (int i = 0; i < 4; ++i)
      af[i] = *(const bf16x8*)(sAb + (wm * 128 + 64 + i * 16 + lr) * 32 + rch);
    if (kt + 2 < NT) {
      stgA(slot, kt + 2, 0); stgA(slot, kt + 2, 2);
      stgB(slot, kt + 2, 0); stgB(slot, kt + 2, 1);
    }
    asm volatile("s_waitcnt lgkmcnt(0)" ::: "memory");
    __builtin_amdgcn_sched_barrier(0);
    __builtin_amdgcn_s_setprio(1);
#pragma unroll
    for (int i = 0; i < 4; ++i)
#pragma unroll
      for (int n = 0; n < 4; ++n)
        acc[4 + i][n] = __builtin_amdgcn_mfma_f32_16x16x32_bf16(af[i], bv[n], acc[4 + i][n], 0, 0, 0);
    __builtin_amdgcn_s_setprio(0);
    // next tile-top barrier closes this phase.
  }

  // epilogue (bf16 out, z-slab)
  const int r0 = bm * 256 + wm * 128, c0 = col0 + wn * 64;
#pragma unroll
  for (int mm = 0; mm < 8; ++mm)
#pragma unroll
    for (int nn = 0; nn < 4; ++nn) {
      const int rr = r0 + mm * 16 + lg * 4;
      const int cc = c0 + nn * 16 + lr;
      bf16* C = Cv + (size_t)z * (Mn * 2048);
#pragma unroll
      for (int r = 0; r < 4; ++r)
        C[(size_t)(rr + r) * 2048 + cc] = __float2bfloat16(acc[mm][nn][r]);
    }
}

// ---------------- GEMM 8F (out-proj): fine-phase, BM=128 BN=256 ------------
// 512 thr = 8 waves (2M x 4N), per-wave 64x64; 3-slot ring, depth-2 counted
// vmcnt(6); f32 direct output. 32 K-tiles; 256 blocks = 1/CU, 8 waves/CU.
template <int NCT>
__global__ __launch_bounds__(512, 1) void gemm8f(const bf16* __restrict__ A,
                                                 const bf16* __restrict__ W,
                                                 float* __restrict__ Cv) {
  constexpr int K = 2048, NT = K / 64;            // 32 K-tiles
  constexpr int SLOTE = (128 + 256) * 64;         // 24576 elems per slot
  __shared__ bf16 smem[3 * SLOTE];                // 147456 B

  constexpr int MT = Mn / 128;                    // 32 row tiles
  const int nwg = MT * NCT;
  const int orig = blockIdx.x;
  const int wgid = (orig & 7) * (nwg >> 3) + (orig >> 3);   // XCD swizzle
  const int bm = wgid / NCT;
  const int bcn = wgid % NCT;
  const int col0 = bcn * 256;

  const int t = threadIdx.x;
  const int wave = t >> 6, lane = t & 63;
  const int wm = wave >> 2, wn = wave & 3;
  const int lr = lane & 15, lg = lane >> 4;
  const int swz = lr & 7;

  const int srow = t >> 3;
  const int schk = (t & 7) ^ (srow & 7);
  const bf16* Ab = A + (size_t)(bm * 128 + srow) * K + schk * 8;
  const bf16* Bb = W + (size_t)(col0 + srow) * K + schk * 8;

  auto stgA = [&](int slot, int kt, int u) {
    gload_lds16(Ab + (size_t)u * 64 * K + kt * 64,
                smem + slot * SLOTE + u * 4096 + t * 8);
  };
  auto stgB = [&](int slot, int kt, int u) {
    gload_lds16(Bb + (size_t)u * 64 * K + kt * 64,
                smem + slot * SLOTE + 8192 + u * 4096 + t * 8);
  };

  f32x4 acc[4][4];
  const f32x4 zf = {0.f, 0.f, 0.f, 0.f};
#pragma unroll
  for (int i = 0; i < 4; ++i)
#pragma unroll
    for (int j = 0; j < 4; ++j) acc[i][j] = zf;

  stgA(0, 0, 0); stgA(0, 0, 1);
  stgB(0, 0, 0); stgB(0, 0, 1); stgB(0, 0, 2); stgB(0, 0, 3);
  stgA(1, 1, 0); stgA(1, 1, 1);
  stgB(1, 1, 0); stgB(1, 1, 1); stgB(1, 1, 2); stgB(1, 1, 3);

  int sl = 0;
#pragma unroll 1
  for (int kt = 0; kt < NT; ++kt) {
    const bf16* sA = smem + sl * SLOTE;
    const bf16* sB = sA + 8192;
    int sl2 = sl + 2; if (sl2 >= 3) sl2 -= 3;
    const bool pf = (kt + 2 < NT);

    if (kt == NT - 1) asm volatile("s_waitcnt vmcnt(0)" ::: "memory");
    else              asm volatile("s_waitcnt vmcnt(6)" ::: "memory");
    __builtin_amdgcn_s_barrier();

    {
      bf16x8 af[4], bv[4];
#pragma unroll
      for (int i = 0; i < 4; ++i)
        af[i] = *(const bf16x8*)(sA + (wm * 64 + i * 16 + lr) * 64 + ((lg ^ swz) * 8));
#pragma unroll
      for (int n = 0; n < 4; ++n)
        bv[n] = *(const bf16x8*)(sB + (wn * 64 + n * 16 + lr) * 64 + ((lg ^ swz) * 8));
      if (pf) { stgA(sl2, kt + 2, 0); stgA(sl2, kt + 2, 1); stgB(sl2, kt + 2, 0); }
      __builtin_amdgcn_s_barrier();
      asm volatile("s_waitcnt lgkmcnt(0)" ::: "memory");
      __builtin_amdgcn_sched_barrier(0);
      __builtin_amdgcn_s_setprio(1);
#pragma unroll
      for (int i = 0; i < 4; ++i)
#pragma unroll
        for (int n = 0; n < 4; ++n)
          acc[i][n] = __builtin_amdgcn_mfma_f32_16x16x32_bf16(af[i], bv[n], acc[i][n], 0, 0, 0);
      __builtin_amdgcn_s_setprio(0);
      __builtin_amdgcn_s_barrier();
    }
    {
      bf16x8 af[4], bv[4];
#pragma unroll
      for (int i = 0; i < 4; ++i)
        af[i] = *(const bf16x8*)(sA + (wm * 64 + i * 16 + lr) * 64 + (((4 + lg) ^ swz) * 8));
#pragma unroll
      for (int n = 0; n < 4; ++n)
        bv[n] = *(const bf16x8*)(sB + (wn * 64 + n * 16 + lr) * 64 + (((4 + lg) ^ swz) * 8));
      if (pf) { stgB(sl2, kt + 2, 1); stgB(sl2, kt + 2, 2); stgB(sl2, kt + 2, 3); }
      __builtin_amdgcn_s_barrier();
      asm volatile("s_waitcnt lgkmcnt(0)" ::: "memory");
      __builtin_amdgcn_sched_barrier(0);
      __builtin_amdgcn_s_setprio(1);
#pragma unroll
      for (int i = 0; i < 4; ++i)
#pragma unroll
        for (int n = 0; n < 4; ++n)
          acc[i][n] = __builtin_amdgcn_mfma_f32_16x16x32_bf16(af[i], bv[n], acc[i][n], 0, 0, 0);
      __builtin_amdgcn_s_setprio(0);
    }
    sl = (sl == 2) ? 0 : sl + 1;
  }

  const int r0 = bm * 128 + wm * 64, c0 = col0 + wn * 64;
#pragma unroll
  for (int mm = 0; mm < 4; ++mm)
#pragma unroll
    for (int nn = 0; nn < 4; ++nn) {
      const int rr = r0 + mm * 16 + lg * 4;
      const int cc = c0 + nn * 16 + lr;
#pragma unroll
      for (int r = 0; r < 4; ++r)
        Cv[(size_t)(rr + r) * 2048 + cc] = acc[mm][nn][r];
    }
}

// ---------------- V transpose: per (b,h)  V[2048,128] -> VT[128,2048] ------
__global__ __launch_bounds__(256, 2) void transpose_v(const bf16* __restrict__ V,
                                                      bf16* __restrict__ VT) {
  __shared__ bf16 tile[128 * 128];   // 32 KB, chunk-XOR-swizzled
  const int kt = blockIdx.x, bh = blockIdx.y;
  const bf16* Vh = V + (size_t)bh * (Sn * DHn);
  bf16* VTh = VT + (size_t)bh * (DHn * Sn);
  const int t = threadIdx.x;
  const int rr = t >> 4, cc = t & 15;
#pragma unroll
  for (int i = 0; i < 8; ++i) {
    int r = rr + i * 16;
    int ch = cc ^ ((r >> 3) & 7);
    *(bf16x8*)(tile + r * 128 + ch * 8) =
        *(const bf16x8*)(Vh + (size_t)(kt * 128 + r) * DHn + cc * 8);
  }
  __syncthreads();
  const int dr = t >> 4, li = t & 15;
#pragma unroll
  for (int i = 0; i < 8; ++i) {
    int dh = dr + i * 16;
    union { bf16 h[8]; bf16x8 v; } u;
#pragma unroll
    for (int j = 0; j < 8; ++j) {
      int k = li * 8 + j;
      int ch = (dh >> 3) ^ ((k >> 3) & 7);
      u.h[j] = tile[k * 128 + ch * 8 + (dh & 7)];
    }
    *(bf16x8*)(VTh + (size_t)dh * Sn + kt * 128 + li * 8) = u.v;
  }
}

// ---------------- causal flash attention v4 --------------------------------
// QBLK=128, 8 waves x 16 q-rows, KBLK=64; pairs qb=j / 15-j; 256 blocks.
// NEW: 3-slot K/V ring + depth-2 prefetch + counted vmcnt (gemmY's proven
// pipeline): tile kt top stages kt+2 into slot (kt+2)%3 (readers were tile
// kt-1, drained before crossing kt's barrier); tile end waits vmcnt(4) when
// kt+2 staged (retire kt+1, keep kt+2 in flight -> ~2 tiles of latency
// slack), vmcnt(0) on tail; ONE raw barrier per tile (also fences sP reuse).
__global__ __launch_bounds__(512, 1) void attn_k4(const bf16* __restrict__ Q,
                                                  const bf16* __restrict__ K,
                                                  const bf16* __restrict__ VT,
                                                  bf16* __restrict__ Mg) {
  __shared__ bf16 smem[57344];         // 112 KB: 3 x (sK 16KB + sV 16KB) + sP 16KB
  bf16* sP = smem + 49152;             // 8 waves x [16][64] swizzled
  bf16* sO = smem;                     // epilogue reuse [128][128] (32 KB)

  const int bi = blockIdx.x;           // XCD-grouped decode
  const int xcd = bi & 7, slt = bi >> 3;
  const int bh = (slt & 3) * 8 + xcd;  // 4 bh per XCD -> 4 MB K/V = L2-resident
  const int j = slt >> 2;              // pair index 0..7
  const bf16* Qh = Q + (size_t)bh * (Sn * DHn);
  const bf16* Kh = K + (size_t)bh * (Sn * DHn);
  const bf16* VTh = VT + (size_t)bh * (DHn * Sn);
  const int b = bh >> 4, h = bh & 15;

  const int t = threadIdx.x, wave = t >> 6, lane = t & 63;
  const int lr = lane & 15, lg = lane >> 4;

  auto STAGE = [&](int s, int kt) {
    bf16* dK = smem + s * 16384;
    bf16* dV = dK + 8192;
#pragma unroll
    for (int i = 0; i < 2; ++i) {
      int c = i * 512 + t;               // 0..1023
      int row = c >> 4, c16 = c & 15;
      gload_lds16(Kh + (size_t)(kt * 64 + row) * DHn + ((c16 ^ (row & 7)) * 8),
                  dK + c * 8);
    }
#pragma unroll
    for (int i = 0; i < 2; ++i) {
      int c = i * 512 + t;
      int row = c >> 3, c8 = c & 7;
      gload_lds16(VTh + (size_t)row * Sn + kt * 64 + ((c8 ^ (row & 7)) * 8),
                  dV + c * 8);
    }
  };

  const f32x4 zf = {0.f, 0.f, 0.f, 0.f};

  for (int pi = 0; pi < 2; ++pi) {
    const int qb = pi ? (15 - j) : j;    // QBLK=128 block index
    const int nt = qb * 2 + 2;
    const int q0 = qb * 128 + wave * 16;

    bf16x8 qf[4];
#pragma unroll
    for (int kk = 0; kk < 4; ++kk)
      qf[kk] = *(const bf16x8*)(Qh + (size_t)(q0 + lr) * DHn + kk * 32 + lg * 8);

    f32x4 o[8];
#pragma unroll
    for (int d = 0; d < 8; ++d) o[d] = zf;
    float mrun[4], lrun[4];
#pragma unroll
    for (int r = 0; r < 4; ++r) { mrun[r] = -3e38f; lrun[r] = 0.f; }

    // prologue: tiles 0,1 in flight; publish tile 0 (tile 1 stays in flight)
    STAGE(0, 0);
    STAGE(1, 1);
    asm volatile("s_waitcnt vmcnt(4)" ::: "memory");
    __builtin_amdgcn_s_barrier();

    for (int kt = 0; kt < nt; ++kt) {
      const int sl = kt % 3;
      if (kt + 2 < nt) STAGE((kt + 2) % 3, kt + 2);   // depth-2 prefetch

      bf16* sKc = smem + sl * 16384;
      bf16* sVc = sKc + 8192;

      // S = Q K^T
      f32x4 sfr[4];
#pragma unroll
      for (int nn = 0; nn < 4; ++nn) sfr[nn] = zf;
#pragma unroll
      for (int kk = 0; kk < 4; ++kk)
#pragma unroll
        for (int nn = 0; nn < 4; ++nn) {
          int row = nn * 16 + lr;
          int ch = (kk * 4 + lg) ^ (row & 7);
          bf16x8 kf = *(const bf16x8*)(sKc + row * DHn + ch * 8);
          sfr[nn] = __builtin_amdgcn_mfma_f32_16x16x32_bf16(qf[kk], kf, sfr[nn], 0, 0, 0);
        }

      // online softmax (rows: lg*4+r, cols: nn*16+lr)
      const bool maskt = (kt >= qb * 2);
      float pv[4][4];
#pragma unroll
      for (int nn = 0; nn < 4; ++nn)
#pragma unroll
        for (int r = 0; r < 4; ++r) {
          float v = sfr[nn][r] * (1.0f / 128.0f);
          if (maskt) {
            int kg = kt * 64 + nn * 16 + lr;
            int qg = q0 + lg * 4 + r;
            if (kg > qg) v = -1e30f;
          }
          pv[nn][r] = v;
        }
      float mnew[4], alpha[4], rsum[4];
#pragma unroll
      for (int r = 0; r < 4; ++r) {
        float rm = fmaxf(fmaxf(pv[0][r], pv[1][r]), fmaxf(pv[2][r], pv[3][r]));
        rm = fmaxf(rm, __shfl_xor(rm, 1));
        rm = fmaxf(rm, __shfl_xor(rm, 2));
        rm = fmaxf(rm, __shfl_xor(rm, 4));
        rm = fmaxf(rm, __shfl_xor(rm, 8));
        mnew[r] = fmaxf(mrun[r], rm);
        alpha[r] = __expf(mrun[r] - mnew[r]);
        mrun[r] = mnew[r];
        rsum[r] = 0.f;
      }
#pragma unroll
      for (int nn = 0; nn < 4; ++nn)
#pragma unroll
        for (int r = 0; r < 4; ++r) {
          float p = __expf(pv[nn][r] - mnew[r]);
          pv[nn][r] = p;
          rsum[r] += p;
        }
#pragma unroll
      for (int r = 0; r < 4; ++r) {
        float s = rsum[r];
        s += __shfl_xor(s, 1); s += __shfl_xor(s, 2);
        s += __shfl_xor(s, 4); s += __shfl_xor(s, 8);
        lrun[r] = lrun[r] * alpha[r] + s;
      }
#pragma unroll
      for (int d = 0; d < 8; ++d)
#pragma unroll
        for (int r = 0; r < 4; ++r) o[d][r] *= alpha[r];

      // P -> LDS (swizzled), per-wave [16][64] region
#pragma unroll
      for (int nn = 0; nn < 4; ++nn)
#pragma unroll
        for (int r = 0; r < 4; ++r) {
          int row = lg * 4 + r;
          int chk = (nn * 2 + (lr >> 3)) ^ (row & 7);
          sP[wave * 1024 + row * 64 + chk * 8 + (lr & 7)] = __float2bfloat16(pv[nn][r]);
        }

      // O += P V
      bf16x8 pf[2];
#pragma unroll
      for (int kk = 0; kk < 2; ++kk) {
        int ch = (kk * 4 + lg) ^ (lr & 7);
        pf[kk] = *(const bf16x8*)(sP + wave * 1024 + lr * 64 + ch * 8);
      }
#pragma unroll
      for (int d = 0; d < 8; ++d)
#pragma unroll
        for (int kk = 0; kk < 2; ++kk) {
          int vrow = d * 16 + lr;
          int vch = (kk * 4 + lg) ^ (vrow & 7);
          bf16x8 vf = *(const bf16x8*)(sVc + vrow * 64 + vch * 8);
          o[d] = __builtin_amdgcn_mfma_f32_16x16x32_bf16(pf[kk], vf, o[d], 0, 0, 0);
        }

      // tile end: retire kt+1's loads (keep kt+2's in flight); publish
      if (kt + 2 < nt) asm volatile("s_waitcnt vmcnt(4)" ::: "memory");
      else             asm volatile("s_waitcnt vmcnt(0)" ::: "memory");
      __builtin_amdgcn_s_barrier();
    }

    // epilogue: normalize, stage to LDS (swizzled), coalesced global write
    float inv[4];
#pragma unroll
    for (int r = 0; r < 4; ++r) inv[r] = 1.0f / lrun[r];
#pragma unroll
    for (int d = 0; d < 8; ++d)
#pragma unroll
      for (int r = 0; r < 4; ++r) {
        int row = wave * 16 + lg * 4 + r;
        int col = d * 16 + lr;
        int chk = ((col >> 3) ^ (row & 7));
        sO[row * 128 + chk * 8 + (col & 7)] = __float2bfloat16(o[d][r] * inv[r]);
      }
    __syncthreads();
    bf16* Mh = Mg + ((size_t)(b * Sn + qb * 128)) * Dn + h * DHn;
#pragma unroll
    for (int i = 0; i < 4; ++i) {
      int row = (t >> 4) + i * 32;
      int c16 = t & 15;
      *(bf16x8*)(Mh + (size_t)row * Dn + c16 * 8) =
          *(const bf16x8*)(sO + row * 128 + ((c16 ^ (row & 7)) * 8));
    }
    __syncthreads();   // sO region is re-staged by next pass
  }
}

// ---------------------------------------------------------------------------
extern "C" void kernel_launch(void* const* d_in, const int* in_sizes, int n_in,
                              void* d_out, int out_size, void* d_ws, size_t ws_size,
                              hipStream_t stream) {
  const float* x = (const float*)d_in[0];
  const float* Wq = (const float*)d_in[1];
  const float* Wk = (const float*)d_in[2];
  const float* Wv = (const float*)d_in[3];
  const float* Wo = (const float*)d_in[4];
  float* out = (float*)d_out;

  char* ws = (char*)d_ws;
  bf16* xb = (bf16*)ws;            ws += (size_t)Mn * Dn * 2;        // 16 MB
  bf16* Wb = (bf16*)ws;            ws += (size_t)4 * Dn * Dn * 2;    // 32 MB (q,k,v,o)
  bf16* QKV = (bf16*)ws;           ws += (size_t)3 * Mn * Dn * 2;    // 48 MB
  bf16* VT = (bf16*)ws;            ws += (size_t)Bn * Hn * DHn * Sn * 2; // 16 MB
  bf16* Mg = (bf16*)ws;            ws += (size_t)Mn * Dn * 2;        // 16 MB

  // all f32->bf16 conversions in one launch
  cvt_all_k<<<dim3(2048, 5), 256, 0, stream>>>(x, Wq, Wk, Wv, Wo, xb, Wb);

  // Q,K,V = x @ W{q,k,v}^T -> bf16 (768 blocks, BM=256)
  gemmY<48, 3><<<768, 256, 0, stream>>>(xb, Wb, QKV);

  // per-head V transpose (plain-view head slabs)
  transpose_v<<<dim3(16, 32), 256, 0, stream>>>(QKV + 2 * (size_t)Mn * Dn, VT);

  // causal attention -> merged [4096, 2048] bf16 (XCD-grouped grid)
  attn_k4<<<256, 512, 0, stream>>>(QKV, QKV + (size_t)Mn * Dn, VT, Mg);

  // out = merged @ Wo^T -> f32 (32 x 8 = 256 blocks = 1/CU, 8 waves)
  gemm8f<8><<<256, 512, 0, stream>>>(Mg, Wb + 3 * (size_t)Dn * Dn, out);
}

// Round 13
// 234.373 us; speedup vs baseline: 1.1376x; 1.0723x over previous
//
#include <hip/hip_runtime.h>
#include <hip/hip_bf16.h>

using bf16 = __hip_bfloat16;
typedef __attribute__((ext_vector_type(8))) short bf16x8;   // 8 bf16 = 4 VGPR
typedef __attribute__((ext_vector_type(4))) float f32x4;    // MFMA C/D frag

#define DEVI __device__ __forceinline__

constexpr int Bn = 2, Sn = 2048, Dn = 2048, Hn = 16, DHn = 128;
constexpr int Mn = Bn * Sn;   // 4096

DEVI void gload_lds16(const bf16* g, bf16* l) {
  __builtin_amdgcn_global_load_lds(
      (__attribute__((address_space(1))) void*)g,
      (__attribute__((address_space(3))) void*)l,
      16, 0, 0);
}

// ---------------- fused f32 -> bf16 convert (x + 4 weights, one launch) ----
__global__ __launch_bounds__(256) void cvt_all_k(const float* __restrict__ x,
                                                 const float* __restrict__ wq,
                                                 const float* __restrict__ wk,
                                                 const float* __restrict__ wv,
                                                 const float* __restrict__ wo,
                                                 bf16* __restrict__ xb,
                                                 bf16* __restrict__ wb) {
  const int which = blockIdx.y;
  const float* src;
  bf16* dst;
  int n8;
  if (which == 0) { src = x;  dst = xb; n8 = Mn * Dn / 8; }
  else {
    src = (which == 1) ? wq : (which == 2) ? wk : (which == 3) ? wv : wo;
    dst = wb + (size_t)(which - 1) * Dn * Dn;
    n8 = Dn * Dn / 8;
  }
  for (int i = blockIdx.x * 256 + threadIdx.x; i < n8; i += gridDim.x * 256) {
    const float4* p = (const float4*)src + (size_t)i * 2;
    float4 a = p[0], b = p[1];
    union { bf16 h[8]; bf16x8 v; } u;
    u.h[0] = __float2bfloat16(a.x); u.h[1] = __float2bfloat16(a.y);
    u.h[2] = __float2bfloat16(a.z); u.h[3] = __float2bfloat16(a.w);
    u.h[4] = __float2bfloat16(b.x); u.h[5] = __float2bfloat16(b.y);
    u.h[6] = __float2bfloat16(b.z); u.h[7] = __float2bfloat16(b.w);
    *((bf16x8*)dst + i) = u.v;
  }
}

// ---------------- GEMM Y (QKV): C = A[M,K] * W[N,K]^T ----------------------
// BM=256, BN=128, BK=32, 256 thr = 4 waves (2M x 2N), per-wave C = 128x64.
// 2-slot LDS ring (48 KB -> 2 blocks/CU), counted vmcnt, phase-spread
// staging, T2 swizzle, T5 setprio.
template <int NTOT, int NMAT>
__global__ __launch_bounds__(256, 2) void gemmY(const bf16* __restrict__ A,
                                                const bf16* __restrict__ W,
                                                bf16* __restrict__ Cv) {
  constexpr int K = 2048, NT = 64;
  __shared__ bf16 smem[2 * 12288];   // 48 KB: per slot A[256][32] + B[128][32]

  const int nwg = NTOT * 16;
  const int orig = blockIdx.x;
  const int wgid = (orig & 7) * (nwg >> 3) + (orig >> 3);   // XCD swizzle (nwg%8==0)
  const int bm = wgid / NTOT;
  const int bnn = wgid % NTOT;
  constexpr int nper = NTOT / NMAT;
  const int z = bnn / nper;
  const int col0 = (bnn % nper) * 128;

  const int t = threadIdx.x;
  const int wave = t >> 6, lane = t & 63;
  const int wm = wave >> 1, wn = wave & 1;
  const int lr = lane & 15, lg = lane >> 4;
  const int rch = ((lg ^ ((lr >> 1) & 3)) * 8);       // swizzled read chunk
  const int srow = t >> 2;                            // staging row in unit
  const int sch = (t & 3) ^ ((t >> 3) & 3);           // pre-swizzled src chunk

  const bf16* Ab = A + (size_t)(bm * 256 + srow) * K + sch * 8;
  const bf16* Bb = W + (size_t)z * (2048 * 2048) +
                   (size_t)(col0 + srow) * K + sch * 8;

  auto stgA = [&](int slot, int kt, int u) {
    gload_lds16(Ab + (size_t)u * 64 * K + kt * 32,
                smem + slot * 12288 + u * 2048 + t * 8);
  };
  auto stgB = [&](int slot, int kt, int v) {
    gload_lds16(Bb + (size_t)v * 64 * K + kt * 32,
                smem + slot * 12288 + 8192 + v * 2048 + t * 8);
  };

  f32x4 acc[8][4];
  const f32x4 zf = {0.f, 0.f, 0.f, 0.f};
#pragma unroll
  for (int i = 0; i < 8; ++i)
#pragma unroll
    for (int j = 0; j < 4; ++j) acc[i][j] = zf;

  // prologue: tile0 complete (6 units), tile1 partial (A0,A2,B0,B1)
  stgA(0, 0, 0); stgA(0, 0, 1); stgA(0, 0, 2); stgA(0, 0, 3);
  stgB(0, 0, 0); stgB(0, 0, 1);
  stgA(1, 1, 0); stgA(1, 1, 2); stgB(1, 1, 0); stgB(1, 1, 1);

#pragma unroll 2
  for (int kt = 0; kt < NT; ++kt) {
    const int slot = kt & 1;
    const bf16* sAb = smem + slot * 12288;
    const bf16* sBb = sAb + 8192;

    if (kt == NT - 1) asm volatile("s_waitcnt vmcnt(0)" ::: "memory");
    else              asm volatile("s_waitcnt vmcnt(4)" ::: "memory");
    __builtin_amdgcn_s_barrier();

    bf16x8 af[4], bv[4];
#pragma unroll
    for (int i = 0; i < 4; ++i)
      af[i] = *(const bf16x8*)(sAb + (wm * 128 + i * 16 + lr) * 32 + rch);
#pragma unroll
    for (int n = 0; n < 4; ++n)
      bv[n] = *(const bf16x8*)(sBb + (wn * 64 + n * 16 + lr) * 32 + rch);
    if (kt + 1 < NT) { stgA(slot ^ 1, kt + 1, 1); stgA(slot ^ 1, kt + 1, 3); }
    asm volatile("s_waitcnt lgkmcnt(0)" ::: "memory");
    __builtin_amdgcn_sched_barrier(0);      // rule 18
    __builtin_amdgcn_s_setprio(1);
#pragma unroll
    for (int i = 0; i < 4; ++i)
#pragma unroll
      for (int n = 0; n < 4; ++n)
        acc[i][n] = __builtin_amdgcn_mfma_f32_16x16x32_bf16(af[i], bv[n], acc[i][n], 0, 0, 0);
    __builtin_amdgcn_s_setprio(0);
    __builtin_amdgcn_s_barrier();           // A0,A2,B0,B1 of slot kt now dead

#pragma unroll
    for (int i = 0; i < 4; ++i)
      af[i] = *(const bf16x8*)(sAb + (wm * 128 + 64 + i * 16 + lr) * 32 + rch);
    if (kt + 2 < NT) {
      stgA(slot, kt + 2, 0); stgA(slot, kt + 2, 2);
      stgB(slot, kt + 2, 0); stgB(slot, kt + 2, 1);
    }
    asm volatile("s_waitcnt lgkmcnt(0)" ::: "memory");
    __builtin_amdgcn_sched_barrier(0);
    __builtin_amdgcn_s_setprio(1);
#pragma unroll
    for (int i = 0; i < 4; ++i)
#pragma unroll
      for (int n = 0; n < 4; ++n)
        acc[4 + i][n] = __builtin_amdgcn_mfma_f32_16x16x32_bf16(af[i], bv[n], acc[4 + i][n], 0, 0, 0);
    __builtin_amdgcn_s_setprio(0);
  }

  // epilogue (bf16 out, z-slab)
  const int r0 = bm * 256 + wm * 128, c0 = col0 + wn * 64;
#pragma unroll
  for (int mm = 0; mm < 8; ++mm)
#pragma unroll
    for (int nn = 0; nn < 4; ++nn) {
      const int rr = r0 + mm * 16 + lg * 4;
      const int cc = c0 + nn * 16 + lr;
      bf16* C = Cv + (size_t)z * (Mn * 2048);
#pragma unroll
      for (int r = 0; r < 4; ++r)
        C[(size_t)(rr + r) * 2048 + cc] = __float2bfloat16(acc[mm][nn][r]);
    }
}

// ---------------- GEMM 8F (out-proj): fine-phase, BM=128 BN=256 ------------
template <int NCT>
__global__ __launch_bounds__(512, 1) void gemm8f(const bf16* __restrict__ A,
                                                 const bf16* __restrict__ W,
                                                 float* __restrict__ Cv) {
  constexpr int K = 2048, NT = K / 64;            // 32 K-tiles
  constexpr int SLOTE = (128 + 256) * 64;         // 24576 elems per slot
  __shared__ bf16 smem[3 * SLOTE];                // 147456 B

  constexpr int MT = Mn / 128;                    // 32 row tiles
  const int nwg = MT * NCT;
  const int orig = blockIdx.x;
  const int wgid = (orig & 7) * (nwg >> 3) + (orig >> 3);   // XCD swizzle
  const int bm = wgid / NCT;
  const int bcn = wgid % NCT;
  const int col0 = bcn * 256;

  const int t = threadIdx.x;
  const int wave = t >> 6, lane = t & 63;
  const int wm = wave >> 2, wn = wave & 3;
  const int lr = lane & 15, lg = lane >> 4;
  const int swz = lr & 7;

  const int srow = t >> 3;
  const int schk = (t & 7) ^ (srow & 7);
  const bf16* Ab = A + (size_t)(bm * 128 + srow) * K + schk * 8;
  const bf16* Bb = W + (size_t)(col0 + srow) * K + schk * 8;

  auto stgA = [&](int slot, int kt, int u) {
    gload_lds16(Ab + (size_t)u * 64 * K + kt * 64,
                smem + slot * SLOTE + u * 4096 + t * 8);
  };
  auto stgB = [&](int slot, int kt, int u) {
    gload_lds16(Bb + (size_t)u * 64 * K + kt * 64,
                smem + slot * SLOTE + 8192 + u * 4096 + t * 8);
  };

  f32x4 acc[4][4];
  const f32x4 zf = {0.f, 0.f, 0.f, 0.f};
#pragma unroll
  for (int i = 0; i < 4; ++i)
#pragma unroll
    for (int j = 0; j < 4; ++j) acc[i][j] = zf;

  stgA(0, 0, 0); stgA(0, 0, 1);
  stgB(0, 0, 0); stgB(0, 0, 1); stgB(0, 0, 2); stgB(0, 0, 3);
  stgA(1, 1, 0); stgA(1, 1, 1);
  stgB(1, 1, 0); stgB(1, 1, 1); stgB(1, 1, 2); stgB(1, 1, 3);

  int sl = 0;
#pragma unroll 1
  for (int kt = 0; kt < NT; ++kt) {
    const bf16* sA = smem + sl * SLOTE;
    const bf16* sB = sA + 8192;
    int sl2 = sl + 2; if (sl2 >= 3) sl2 -= 3;
    const bool pf = (kt + 2 < NT);

    if (kt == NT - 1) asm volatile("s_waitcnt vmcnt(0)" ::: "memory");
    else              asm volatile("s_waitcnt vmcnt(6)" ::: "memory");
    __builtin_amdgcn_s_barrier();

    {
      bf16x8 af[4], bv[4];
#pragma unroll
      for (int i = 0; i < 4; ++i)
        af[i] = *(const bf16x8*)(sA + (wm * 64 + i * 16 + lr) * 64 + ((lg ^ swz) * 8));
#pragma unroll
      for (int n = 0; n < 4; ++n)
        bv[n] = *(const bf16x8*)(sB + (wn * 64 + n * 16 + lr) * 64 + ((lg ^ swz) * 8));
      if (pf) { stgA(sl2, kt + 2, 0); stgA(sl2, kt + 2, 1); stgB(sl2, kt + 2, 0); }
      __builtin_amdgcn_s_barrier();
      asm volatile("s_waitcnt lgkmcnt(0)" ::: "memory");
      __builtin_amdgcn_sched_barrier(0);
      __builtin_amdgcn_s_setprio(1);
#pragma unroll
      for (int i = 0; i < 4; ++i)
#pragma unroll
        for (int n = 0; n < 4; ++n)
          acc[i][n] = __builtin_amdgcn_mfma_f32_16x16x32_bf16(af[i], bv[n], acc[i][n], 0, 0, 0);
      __builtin_amdgcn_s_setprio(0);
      __builtin_amdgcn_s_barrier();
    }
    {
      bf16x8 af[4], bv[4];
#pragma unroll
      for (int i = 0; i < 4; ++i)
        af[i] = *(const bf16x8*)(sA + (wm * 64 + i * 16 + lr) * 64 + (((4 + lg) ^ swz) * 8));
#pragma unroll
      for (int n = 0; n < 4; ++n)
        bv[n] = *(const bf16x8*)(sB + (wn * 64 + n * 16 + lr) * 64 + (((4 + lg) ^ swz) * 8));
      if (pf) { stgB(sl2, kt + 2, 1); stgB(sl2, kt + 2, 2); stgB(sl2, kt + 2, 3); }
      __builtin_amdgcn_s_barrier();
      asm volatile("s_waitcnt lgkmcnt(0)" ::: "memory");
      __builtin_amdgcn_sched_barrier(0);
      __builtin_amdgcn_s_setprio(1);
#pragma unroll
      for (int i = 0; i < 4; ++i)
#pragma unroll
        for (int n = 0; n < 4; ++n)
          acc[i][n] = __builtin_amdgcn_mfma_f32_16x16x32_bf16(af[i], bv[n], acc[i][n], 0, 0, 0);
      __builtin_amdgcn_s_setprio(0);
    }
    sl = (sl == 2) ? 0 : sl + 1;
  }

  const int r0 = bm * 128 + wm * 64, c0 = col0 + wn * 64;
#pragma unroll
  for (int mm = 0; mm < 4; ++mm)
#pragma unroll
    for (int nn = 0; nn < 4; ++nn) {
      const int rr = r0 + mm * 16 + lg * 4;
      const int cc = c0 + nn * 16 + lr;
#pragma unroll
      for (int r = 0; r < 4; ++r)
        Cv[(size_t)(rr + r) * 2048 + cc] = acc[mm][nn][r];
    }
}

// ---------------- V transpose: per (b,h)  V[2048,128] -> VT[128,2048] ------
__global__ __launch_bounds__(256, 2) void transpose_v(const bf16* __restrict__ V,
                                                      bf16* __restrict__ VT) {
  __shared__ bf16 tile[128 * 128];   // 32 KB, chunk-XOR-swizzled
  const int kt = blockIdx.x, bh = blockIdx.y;
  const bf16* Vh = V + (size_t)bh * (Sn * DHn);
  bf16* VTh = VT + (size_t)bh * (DHn * Sn);
  const int t = threadIdx.x;
  const int rr = t >> 4, cc = t & 15;
#pragma unroll
  for (int i = 0; i < 8; ++i) {
    int r = rr + i * 16;
    int ch = cc ^ ((r >> 3) & 7);
    *(bf16x8*)(tile + r * 128 + ch * 8) =
        *(const bf16x8*)(Vh + (size_t)(kt * 128 + r) * DHn + cc * 8);
  }
  __syncthreads();
  const int dr = t >> 4, li = t & 15;
#pragma unroll
  for (int i = 0; i < 8; ++i) {
    int dh = dr + i * 16;
    union { bf16 h[8]; bf16x8 v; } u;
#pragma unroll
    for (int j = 0; j < 8; ++j) {
      int k = li * 8 + j;
      int ch = (dh >> 3) ^ ((k >> 3) & 7);
      u.h[j] = tile[k * 128 + ch * 8 + (dh & 7)];
    }
    *(bf16x8*)(VTh + (size_t)dh * Sn + kt * 128 + li * 8) = u.v;
  }
}

// ---------------- causal flash attention v5 (swapped-operand softmax) ------
// QBLK=128, 8 waves x 16 q-rows, KBLK=64; pairs qb=j / 15-j; 256 blocks.
// 3-slot K/V ring + depth-2 counted-vmcnt pipeline (from v4).
// NEW: S^T = mfma(A=K, B=Q) -> each lane owns 16 k-scores for ONE q (=q0+lr)
// -> softmax max/sum = in-reg + 2 shfl_xor (lane^16, lane^32), mrun/lrun/
// alpha scalar per lane. PV swapped too: O = mfma(A=V^T, B=P) -> O cols = q
// = lr, so rescale/normalize are scalar ops. Shfl count/tile: 32 -> 4.
__global__ __launch_bounds__(512, 1) void attn_k5(const bf16* __restrict__ Q,
                                                  const bf16* __restrict__ K,
                                                  const bf16* __restrict__ VT,
                                                  bf16* __restrict__ Mg) {
  __shared__ bf16 smem[57344];         // 112 KB: 3 x (sK 16KB + sV 16KB) + sP 16KB
  bf16* sP = smem + 49152;             // 8 waves x [q=16][k=64] swizzled
  bf16* sO = smem;                     // epilogue reuse [128][128] (32 KB)

  const int bi = blockIdx.x;           // XCD-grouped decode
  const int xcd = bi & 7, slt = bi >> 3;
  const int bh = (slt & 3) * 8 + xcd;  // 4 bh per XCD -> K/V L2-resident
  const int j = slt >> 2;              // pair index 0..7
  const bf16* Qh = Q + (size_t)bh * (Sn * DHn);
  const bf16* Kh = K + (size_t)bh * (Sn * DHn);
  const bf16* VTh = VT + (size_t)bh * (DHn * Sn);
  const int b = bh >> 4, h = bh & 15;

  const int t = threadIdx.x, wave = t >> 6, lane = t & 63;
  const int lr = lane & 15, lg = lane >> 4;

  auto STAGE = [&](int s, int kt) {
    bf16* dK = smem + s * 16384;
    bf16* dV = dK + 8192;
#pragma unroll
    for (int i = 0; i < 2; ++i) {
      int c = i * 512 + t;               // 0..1023
      int row = c >> 4, c16 = c & 15;
      gload_lds16(Kh + (size_t)(kt * 64 + row) * DHn + ((c16 ^ (row & 7)) * 8),
                  dK + c * 8);
    }
#pragma unroll
    for (int i = 0; i < 2; ++i) {
      int c = i * 512 + t;
      int row = c >> 3, c8 = c & 7;
      gload_lds16(VTh + (size_t)row * Sn + kt * 64 + ((c8 ^ (row & 7)) * 8),
                  dV + c * 8);
    }
  };

  const f32x4 zf = {0.f, 0.f, 0.f, 0.f};

  for (int pi = 0; pi < 2; ++pi) {
    const int qb = pi ? (15 - j) : j;    // QBLK=128 block index
    const int nt = qb * 2 + 2;
    const int q0 = qb * 128 + wave * 16;
    const int qg = q0 + lr;              // THE q this lane owns (softmax axis)

    bf16x8 qf[4];
#pragma unroll
    for (int kk = 0; kk < 4; ++kk)
      qf[kk] = *(const bf16x8*)(Qh + (size_t)(q0 + lr) * DHn + kk * 32 + lg * 8);

    f32x4 o[8];
#pragma unroll
    for (int d = 0; d < 8; ++d) o[d] = zf;
    float mrun = -3e38f, lrun = 0.f;

    // prologue: tiles 0,1 in flight; publish tile 0 (tile 1 stays in flight)
    STAGE(0, 0);
    STAGE(1, 1);
    asm volatile("s_waitcnt vmcnt(4)" ::: "memory");
    __builtin_amdgcn_s_barrier();

    for (int kt = 0; kt < nt; ++kt) {
      const int sl = kt % 3;
      if (kt + 2 < nt) STAGE((kt + 2) % 3, kt + 2);   // depth-2 prefetch

      bf16* sKc = smem + sl * 16384;
      bf16* sVc = sKc + 8192;

      // S^T = K Q^T : sfr[nn] rows = k (nn*16+lg*4+r), cols = q (lr)
      f32x4 sfr[4];
#pragma unroll
      for (int nn = 0; nn < 4; ++nn) sfr[nn] = zf;
#pragma unroll
      for (int kk = 0; kk < 4; ++kk)
#pragma unroll
        for (int nn = 0; nn < 4; ++nn) {
          int row = nn * 16 + lr;
          int ch = (kk * 4 + lg) ^ (row & 7);
          bf16x8 kf = *(const bf16x8*)(sKc + row * DHn + ch * 8);
          sfr[nn] = __builtin_amdgcn_mfma_f32_16x16x32_bf16(kf, qf[kk], sfr[nn], 0, 0, 0);
        }

      // per-lane softmax for q = qg; lane holds k = kt*64 + nn*16 + lg*4 + r
      const bool maskt = (kt >= qb * 2);
      float pv[4][4];
#pragma unroll
      for (int nn = 0; nn < 4; ++nn)
#pragma unroll
        for (int r = 0; r < 4; ++r) {
          float v = sfr[nn][r] * (1.0f / 128.0f);
          if (maskt) {
            int kg = kt * 64 + nn * 16 + lg * 4 + r;
            if (kg > qg) v = -1e30f;
          }
          pv[nn][r] = v;
        }
      float rm = -3e38f;
#pragma unroll
      for (int nn = 0; nn < 4; ++nn)
        rm = fmaxf(rm, fmaxf(fmaxf(pv[nn][0], pv[nn][1]), fmaxf(pv[nn][2], pv[nn][3])));
      rm = fmaxf(rm, __shfl_xor(rm, 16));
      rm = fmaxf(rm, __shfl_xor(rm, 32));
      const float mnew = fmaxf(mrun, rm);
      const float alpha = __expf(mrun - mnew);
      float rsum = 0.f;
#pragma unroll
      for (int nn = 0; nn < 4; ++nn)
#pragma unroll
        for (int r = 0; r < 4; ++r) {
          float p = __expf(pv[nn][r] - mnew);
          pv[nn][r] = p;
          rsum += p;
        }
      rsum += __shfl_xor(rsum, 16);
      rsum += __shfl_xor(rsum, 32);
      lrun = lrun * alpha + rsum;
      const bool grew = (mnew > mrun);
      mrun = mnew;
      if (__any(grew)) {
#pragma unroll
        for (int d = 0; d < 8; ++d)
#pragma unroll
          for (int r = 0; r < 4; ++r) o[d][r] *= alpha;
      }

      // P -> sP[wave][q=lr][k] (chunk-XOR swizzled on k by lr&7)
#pragma unroll
      for (int nn = 0; nn < 4; ++nn)
#pragma unroll
        for (int r = 0; r < 4; ++r) {
          int c = nn * 2 + (lg >> 1);              // k>>3
          int chk = c ^ (lr & 7);
          sP[wave * 1024 + lr * 64 + chk * 8 + (lg & 1) * 4 + r] =
              __float2bfloat16(pv[nn][r]);
        }

      // O^T += V^T P : o[d] rows = d-offset (lg*4+r), cols = q (lr)
      bf16x8 pf[2];
#pragma unroll
      for (int kk = 0; kk < 2; ++kk) {
        int ch = (kk * 4 + lg) ^ (lr & 7);
        pf[kk] = *(const bf16x8*)(sP + wave * 1024 + lr * 64 + ch * 8);
      }
#pragma unroll
      for (int d = 0; d < 8; ++d)
#pragma unroll
        for (int kk = 0; kk < 2; ++kk) {
          int vrow = d * 16 + lr;
          int vch = (kk * 4 + lg) ^ (vrow & 7);
          bf16x8 vf = *(const bf16x8*)(sVc + vrow * 64 + vch * 8);
          o[d] = __builtin_amdgcn_mfma_f32_16x16x32_bf16(vf, pf[kk], o[d], 0, 0, 0);
        }

      // tile end: retire kt+1's loads (keep kt+2's in flight); publish
      if (kt + 2 < nt) asm volatile("s_waitcnt vmcnt(4)" ::: "memory");
      else             asm volatile("s_waitcnt vmcnt(0)" ::: "memory");
      __builtin_amdgcn_s_barrier();
    }

    // epilogue: normalize (scalar), stage to sO[q][d] (swizzled), store
    const float inv = 1.0f / lrun;
#pragma unroll
    for (int d = 0; d < 8; ++d)
#pragma unroll
      for (int r = 0; r < 4; ++r) {
        int row = wave * 16 + lr;                  // q row; row&7 == lr&7
        int col = d * 16 + lg * 4 + r;             // d col
        int chk = (col >> 3) ^ (lr & 7);
        sO[row * 128 + chk * 8 + (col & 7)] = __float2bfloat16(o[d][r] * inv);
      }
    __syncthreads();
    bf16* Mh = Mg + ((size_t)(b * Sn + qb * 128)) * Dn + h * DHn;
#pragma unroll
    for (int i = 0; i < 4; ++i) {
      int row = (t >> 4) + i * 32;
      int c16 = t & 15;
      *(bf16x8*)(Mh + (size_t)row * Dn + c16 * 8) =
          *(const bf16x8*)(sO + row * 128 + ((c16 ^ (row & 7)) * 8));
    }
    __syncthreads();   // sO region is re-staged by next pass
  }
}

// ---------------------------------------------------------------------------
extern "C" void kernel_launch(void* const* d_in, const int* in_sizes, int n_in,
                              void* d_out, int out_size, void* d_ws, size_t ws_size,
                              hipStream_t stream) {
  const float* x = (const float*)d_in[0];
  const float* Wq = (const float*)d_in[1];
  const float* Wk = (const float*)d_in[2];
  const float* Wv = (const float*)d_in[3];
  const float* Wo = (const float*)d_in[4];
  float* out = (float*)d_out;

  char* ws = (char*)d_ws;
  bf16* xb = (bf16*)ws;            ws += (size_t)Mn * Dn * 2;        // 16 MB
  bf16* Wb = (bf16*)ws;            ws += (size_t)4 * Dn * Dn * 2;    // 32 MB (q,k,v,o)
  bf16* QKV = (bf16*)ws;           ws += (size_t)3 * Mn * Dn * 2;    // 48 MB
  bf16* VT = (bf16*)ws;            ws += (size_t)Bn * Hn * DHn * Sn * 2; // 16 MB
  bf16* Mg = (bf16*)ws;            ws += (size_t)Mn * Dn * 2;        // 16 MB

  // all f32->bf16 conversions in one launch
  cvt_all_k<<<dim3(2048, 5), 256, 0, stream>>>(x, Wq, Wk, Wv, Wo, xb, Wb);

  // Q,K,V = x @ W{q,k,v}^T -> bf16 (768 blocks, BM=256)
  gemmY<48, 3><<<768, 256, 0, stream>>>(xb, Wb, QKV);

  // per-head V transpose (plain-view head slabs)
  transpose_v<<<dim3(16, 32), 256, 0, stream>>>(QKV + 2 * (size_t)Mn * Dn, VT);

  // causal attention -> merged [4096, 2048] bf16 (XCD-grouped grid)
  attn_k5<<<256, 512, 0, stream>>>(QKV, QKV + (size_t)Mn * Dn, VT, Mg);

  // out = merged @ Wo^T -> f32 (32 x 8 = 256 blocks = 1/CU, 8 waves)
  gemm8f<8><<<256, 512, 0, stream>>>(Mg, Wb + 3 * (size_t)Dn * Dn, out);
}

// Round 14
// 227.336 us; speedup vs baseline: 1.1728x; 1.0310x over previous
//
#include <hip/hip_runtime.h>
#include <hip/hip_bf16.h>

using bf16 = __hip_bfloat16;
typedef __attribute__((ext_vector_type(8))) short bf16x8;   // 8 bf16 = 4 VGPR
typedef __attribute__((ext_vector_type(4))) float f32x4;    // MFMA C/D frag

#define DEVI __device__ __forceinline__

constexpr int Bn = 2, Sn = 2048, Dn = 2048, Hn = 16, DHn = 128;
constexpr int Mn = Bn * Sn;   // 4096

DEVI void gload_lds16(const bf16* g, bf16* l) {
  __builtin_amdgcn_global_load_lds(
      (__attribute__((address_space(1))) void*)g,
      (__attribute__((address_space(3))) void*)l,
      16, 0, 0);
}

// ---------------- fused f32 -> bf16 convert (x + 4 weights, one launch) ----
__global__ __launch_bounds__(256) void cvt_all_k(const float* __restrict__ x,
                                                 const float* __restrict__ wq,
                                                 const float* __restrict__ wk,
                                                 const float* __restrict__ wv,
                                                 const float* __restrict__ wo,
                                                 bf16* __restrict__ xb,
                                                 bf16* __restrict__ wb) {
  const int which = blockIdx.y;
  const float* src;
  bf16* dst;
  int n8;
  if (which == 0) { src = x;  dst = xb; n8 = Mn * Dn / 8; }
  else {
    src = (which == 1) ? wq : (which == 2) ? wk : (which == 3) ? wv : wo;
    dst = wb + (size_t)(which - 1) * Dn * Dn;
    n8 = Dn * Dn / 8;
  }
  for (int i = blockIdx.x * 256 + threadIdx.x; i < n8; i += gridDim.x * 256) {
    const float4* p = (const float4*)src + (size_t)i * 2;
    float4 a = p[0], b = p[1];
    union { bf16 h[8]; bf16x8 v; } u;
    u.h[0] = __float2bfloat16(a.x); u.h[1] = __float2bfloat16(a.y);
    u.h[2] = __float2bfloat16(a.z); u.h[3] = __float2bfloat16(a.w);
    u.h[4] = __float2bfloat16(b.x); u.h[5] = __float2bfloat16(b.y);
    u.h[6] = __float2bfloat16(b.z); u.h[7] = __float2bfloat16(b.w);
    *((bf16x8*)dst + i) = u.v;
  }
}

// ---------------- GEMM Y (QKV): C = A[M,K] * W[N,K]^T ----------------------
// BM=256, BN=128, BK=32, 256 thr = 4 waves (2M x 2N), per-wave C = 128x64.
// 2-slot LDS ring (48 KB), counted vmcnt, phase-spread staging, T2 swizzle,
// T5 setprio.
template <int NTOT, int NMAT>
__global__ __launch_bounds__(256, 2) void gemmY(const bf16* __restrict__ A,
                                                const bf16* __restrict__ W,
                                                bf16* __restrict__ Cv) {
  constexpr int K = 2048, NT = 64;
  __shared__ bf16 smem[2 * 12288];   // 48 KB: per slot A[256][32] + B[128][32]

  const int nwg = NTOT * 16;
  const int orig = blockIdx.x;
  const int wgid = (orig & 7) * (nwg >> 3) + (orig >> 3);   // XCD swizzle (nwg%8==0)
  const int bm = wgid / NTOT;
  const int bnn = wgid % NTOT;
  constexpr int nper = NTOT / NMAT;
  const int z = bnn / nper;
  const int col0 = (bnn % nper) * 128;

  const int t = threadIdx.x;
  const int wave = t >> 6, lane = t & 63;
  const int wm = wave >> 1, wn = wave & 1;
  const int lr = lane & 15, lg = lane >> 4;
  const int rch = ((lg ^ ((lr >> 1) & 3)) * 8);       // swizzled read chunk
  const int srow = t >> 2;                            // staging row in unit
  const int sch = (t & 3) ^ ((t >> 3) & 3);           // pre-swizzled src chunk

  const bf16* Ab = A + (size_t)(bm * 256 + srow) * K + sch * 8;
  const bf16* Bb = W + (size_t)z * (2048 * 2048) +
                   (size_t)(col0 + srow) * K + sch * 8;

  auto stgA = [&](int slot, int kt, int u) {
    gload_lds16(Ab + (size_t)u * 64 * K + kt * 32,
                smem + slot * 12288 + u * 2048 + t * 8);
  };
  auto stgB = [&](int slot, int kt, int v) {
    gload_lds16(Bb + (size_t)v * 64 * K + kt * 32,
                smem + slot * 12288 + 8192 + v * 2048 + t * 8);
  };

  f32x4 acc[8][4];
  const f32x4 zf = {0.f, 0.f, 0.f, 0.f};
#pragma unroll
  for (int i = 0; i < 8; ++i)
#pragma unroll
    for (int j = 0; j < 4; ++j) acc[i][j] = zf;

  // prologue: tile0 complete (6 units), tile1 partial (A0,A2,B0,B1)
  stgA(0, 0, 0); stgA(0, 0, 1); stgA(0, 0, 2); stgA(0, 0, 3);
  stgB(0, 0, 0); stgB(0, 0, 1);
  stgA(1, 1, 0); stgA(1, 1, 2); stgB(1, 1, 0); stgB(1, 1, 1);

#pragma unroll 2
  for (int kt = 0; kt < NT; ++kt) {
    const int slot = kt & 1;
    const bf16* sAb = smem + slot * 12288;
    const bf16* sBb = sAb + 8192;

    if (kt == NT - 1) asm volatile("s_waitcnt vmcnt(0)" ::: "memory");
    else              asm volatile("s_waitcnt vmcnt(4)" ::: "memory");
    __builtin_amdgcn_s_barrier();

    bf16x8 af[4], bv[4];
#pragma unroll
    for (int i = 0; i < 4; ++i)
      af[i] = *(const bf16x8*)(sAb + (wm * 128 + i * 16 + lr) * 32 + rch);
#pragma unroll
    for (int n = 0; n < 4; ++n)
      bv[n] = *(const bf16x8*)(sBb + (wn * 64 + n * 16 + lr) * 32 + rch);
    if (kt + 1 < NT) { stgA(slot ^ 1, kt + 1, 1); stgA(slot ^ 1, kt + 1, 3); }
    asm volatile("s_waitcnt lgkmcnt(0)" ::: "memory");
    __builtin_amdgcn_sched_barrier(0);      // rule 18
    __builtin_amdgcn_s_setprio(1);
#pragma unroll
    for (int i = 0; i < 4; ++i)
#pragma unroll
      for (int n = 0; n < 4; ++n)
        acc[i][n] = __builtin_amdgcn_mfma_f32_16x16x32_bf16(af[i], bv[n], acc[i][n], 0, 0, 0);
    __builtin_amdgcn_s_setprio(0);
    __builtin_amdgcn_s_barrier();           // A0,A2,B0,B1 of slot kt now dead

#pragma unroll
    for (int i = 0; i < 4; ++i)
      af[i] = *(const bf16x8*)(sAb + (wm * 128 + 64 + i * 16 + lr) * 32 + rch);
    if (kt + 2 < NT) {
      stgA(slot, kt + 2, 0); stgA(slot, kt + 2, 2);
      stgB(slot, kt + 2, 0); stgB(slot, kt + 2, 1);
    }
    asm volatile("s_waitcnt lgkmcnt(0)" ::: "memory");
    __builtin_amdgcn_sched_barrier(0);
    __builtin_amdgcn_s_setprio(1);
#pragma unroll
    for (int i = 0; i < 4; ++i)
#pragma unroll
      for (int n = 0; n < 4; ++n)
        acc[4 + i][n] = __builtin_amdgcn_mfma_f32_16x16x32_bf16(af[i], bv[n], acc[4 + i][n], 0, 0, 0);
    __builtin_amdgcn_s_setprio(0);
  }

  // epilogue (bf16 out, z-slab)
  const int r0 = bm * 256 + wm * 128, c0 = col0 + wn * 64;
#pragma unroll
  for (int mm = 0; mm < 8; ++mm)
#pragma unroll
    for (int nn = 0; nn < 4; ++nn) {
      const int rr = r0 + mm * 16 + lg * 4;
      const int cc = c0 + nn * 16 + lr;
      bf16* C = Cv + (size_t)z * (Mn * 2048);
#pragma unroll
      for (int r = 0; r < 4; ++r)
        C[(size_t)(rr + r) * 2048 + cc] = __float2bfloat16(acc[mm][nn][r]);
    }
}

// ---------------- GEMM 8F (out-proj): fine-phase, BM=128 BN=256 ------------
template <int NCT>
__global__ __launch_bounds__(512, 1) void gemm8f(const bf16* __restrict__ A,
                                                 const bf16* __restrict__ W,
                                                 float* __restrict__ Cv) {
  constexpr int K = 2048, NT = K / 64;            // 32 K-tiles
  constexpr int SLOTE = (128 + 256) * 64;         // 24576 elems per slot
  __shared__ bf16 smem[3 * SLOTE];                // 147456 B

  constexpr int MT = Mn / 128;                    // 32 row tiles
  const int nwg = MT * NCT;
  const int orig = blockIdx.x;
  const int wgid = (orig & 7) * (nwg >> 3) + (orig >> 3);   // XCD swizzle
  const int bm = wgid / NCT;
  const int bcn = wgid % NCT;
  const int col0 = bcn * 256;

  const int t = threadIdx.x;
  const int wave = t >> 6, lane = t & 63;
  const int wm = wave >> 2, wn = wave & 3;
  const int lr = lane & 15, lg = lane >> 4;
  const int swz = lr & 7;

  const int srow = t >> 3;
  const int schk = (t & 7) ^ (srow & 7);
  const bf16* Ab = A + (size_t)(bm * 128 + srow) * K + schk * 8;
  const bf16* Bb = W + (size_t)(col0 + srow) * K + schk * 8;

  auto stgA = [&](int slot, int kt, int u) {
    gload_lds16(Ab + (size_t)u * 64 * K + kt * 64,
                smem + slot * SLOTE + u * 4096 + t * 8);
  };
  auto stgB = [&](int slot, int kt, int u) {
    gload_lds16(Bb + (size_t)u * 64 * K + kt * 64,
                smem + slot * SLOTE + 8192 + u * 4096 + t * 8);
  };

  f32x4 acc[4][4];
  const f32x4 zf = {0.f, 0.f, 0.f, 0.f};
#pragma unroll
  for (int i = 0; i < 4; ++i)
#pragma unroll
    for (int j = 0; j < 4; ++j) acc[i][j] = zf;

  stgA(0, 0, 0); stgA(0, 0, 1);
  stgB(0, 0, 0); stgB(0, 0, 1); stgB(0, 0, 2); stgB(0, 0, 3);
  stgA(1, 1, 0); stgA(1, 1, 1);
  stgB(1, 1, 0); stgB(1, 1, 1); stgB(1, 1, 2); stgB(1, 1, 3);

  int sl = 0;
#pragma unroll 1
  for (int kt = 0; kt < NT; ++kt) {
    const bf16* sA = smem + sl * SLOTE;
    const bf16* sB = sA + 8192;
    int sl2 = sl + 2; if (sl2 >= 3) sl2 -= 3;
    const bool pf = (kt + 2 < NT);

    if (kt == NT - 1) asm volatile("s_waitcnt vmcnt(0)" ::: "memory");
    else              asm volatile("s_waitcnt vmcnt(6)" ::: "memory");
    __builtin_amdgcn_s_barrier();

    {
      bf16x8 af[4], bv[4];
#pragma unroll
      for (int i = 0; i < 4; ++i)
        af[i] = *(const bf16x8*)(sA + (wm * 64 + i * 16 + lr) * 64 + ((lg ^ swz) * 8));
#pragma unroll
      for (int n = 0; n < 4; ++n)
        bv[n] = *(const bf16x8*)(sB + (wn * 64 + n * 16 + lr) * 64 + ((lg ^ swz) * 8));
      if (pf) { stgA(sl2, kt + 2, 0); stgA(sl2, kt + 2, 1); stgB(sl2, kt + 2, 0); }
      __builtin_amdgcn_s_barrier();
      asm volatile("s_waitcnt lgkmcnt(0)" ::: "memory");
      __builtin_amdgcn_sched_barrier(0);
      __builtin_amdgcn_s_setprio(1);
#pragma unroll
      for (int i = 0; i < 4; ++i)
#pragma unroll
        for (int n = 0; n < 4; ++n)
          acc[i][n] = __builtin_amdgcn_mfma_f32_16x16x32_bf16(af[i], bv[n], acc[i][n], 0, 0, 0);
      __builtin_amdgcn_s_setprio(0);
      __builtin_amdgcn_s_barrier();
    }
    {
      bf16x8 af[4], bv[4];
#pragma unroll
      for (int i = 0; i < 4; ++i)
        af[i] = *(const bf16x8*)(sA + (wm * 64 + i * 16 + lr) * 64 + (((4 + lg) ^ swz) * 8));
#pragma unroll
      for (int n = 0; n < 4; ++n)
        bv[n] = *(const bf16x8*)(sB + (wn * 64 + n * 16 + lr) * 64 + (((4 + lg) ^ swz) * 8));
      if (pf) { stgB(sl2, kt + 2, 1); stgB(sl2, kt + 2, 2); stgB(sl2, kt + 2, 3); }
      __builtin_amdgcn_s_barrier();
      asm volatile("s_waitcnt lgkmcnt(0)" ::: "memory");
      __builtin_amdgcn_sched_barrier(0);
      __builtin_amdgcn_s_setprio(1);
#pragma unroll
      for (int i = 0; i < 4; ++i)
#pragma unroll
        for (int n = 0; n < 4; ++n)
          acc[i][n] = __builtin_amdgcn_mfma_f32_16x16x32_bf16(af[i], bv[n], acc[i][n], 0, 0, 0);
      __builtin_amdgcn_s_setprio(0);
    }
    sl = (sl == 2) ? 0 : sl + 1;
  }

  const int r0 = bm * 128 + wm * 64, c0 = col0 + wn * 64;
#pragma unroll
  for (int mm = 0; mm < 4; ++mm)
#pragma unroll
    for (int nn = 0; nn < 4; ++nn) {
      const int rr = r0 + mm * 16 + lg * 4;
      const int cc = c0 + nn * 16 + lr;
#pragma unroll
      for (int r = 0; r < 4; ++r)
        Cv[(size_t)(rr + r) * 2048 + cc] = acc[mm][nn][r];
    }
}

// ---------------- V transpose: per (b,h)  V[2048,128] -> VT[128,2048] ------
__global__ __launch_bounds__(256, 2) void transpose_v(const bf16* __restrict__ V,
                                                      bf16* __restrict__ VT) {
  __shared__ bf16 tile[128 * 128];   // 32 KB, chunk-XOR-swizzled
  const int kt = blockIdx.x, bh = blockIdx.y;
  const bf16* Vh = V + (size_t)bh * (Sn * DHn);
  bf16* VTh = VT + (size_t)bh * (DHn * Sn);
  const int t = threadIdx.x;
  const int rr = t >> 4, cc = t & 15;
#pragma unroll
  for (int i = 0; i < 8; ++i) {
    int r = rr + i * 16;
    int ch = cc ^ ((r >> 3) & 7);
    *(bf16x8*)(tile + r * 128 + ch * 8) =
        *(const bf16x8*)(Vh + (size_t)(kt * 128 + r) * DHn + cc * 8);
  }
  __syncthreads();
  const int dr = t >> 4, li = t & 15;
#pragma unroll
  for (int i = 0; i < 8; ++i) {
    int dh = dr + i * 16;
    union { bf16 h[8]; bf16x8 v; } u;
#pragma unroll
    for (int j = 0; j < 8; ++j) {
      int k = li * 8 + j;
      int ch = (dh >> 3) ^ ((k >> 3) & 7);
      u.h[j] = tile[k * 128 + ch * 8 + (dh & 7)];
    }
    *(bf16x8*)(VTh + (size_t)dh * Sn + kt * 128 + li * 8) = u.v;
  }
}

// ---------------- causal flash attention v6 (KBLK=128) ---------------------
// QBLK=128, 8 waves x 16 q-rows, KBLK=128; pairs qb=j / 15-j (17 tiles each;
// 256 blocks). Swapped-operand softmax (per-lane scalar m/l, 4 shfl/tile).
// 2-slot K/V ring (64 KB/slot) + sP 16 KB = 144 KB. Depth-1 prefetch: issue
// kt+1 at tile top into slot^1 (its readers drained before the kt-1 end
// barrier), drain vmcnt(0) at tile end. PV runs in two k-halves sharing the
// per-wave sP[16][64] region (lgkm-ordered within the wave).
__global__ __launch_bounds__(512, 1) void attn_k6(const bf16* __restrict__ Q,
                                                  const bf16* __restrict__ K,
                                                  const bf16* __restrict__ VT,
                                                  bf16* __restrict__ Mg) {
  __shared__ bf16 smem[73728];         // 144 KB: 2 x (sK 32KB + sV 32KB) + sP 16KB
  bf16* sP = smem + 65536;             // 8 waves x [q=16][k=64] swizzled
  bf16* sO = smem;                     // epilogue reuse [128][128] (32 KB)

  const int bi = blockIdx.x;           // XCD-grouped decode
  const int xcd = bi & 7, slt = bi >> 3;
  const int bh = (slt & 3) * 8 + xcd;  // 4 bh per XCD -> K/V L2-resident
  const int j = slt >> 2;              // pair index 0..7
  const bf16* Qh = Q + (size_t)bh * (Sn * DHn);
  const bf16* Kh = K + (size_t)bh * (Sn * DHn);
  const bf16* VTh = VT + (size_t)bh * (DHn * Sn);
  const int b = bh >> 4, h = bh & 15;

  const int t = threadIdx.x, wave = t >> 6, lane = t & 63;
  const int lr = lane & 15, lg = lane >> 4;

  // stage K[128][128] + VT[128][128-k-slice] (chunk-XOR swizzled, linear dst)
  auto STAGE = [&](int s, int kt) {
    bf16* dK = smem + s * 32768;
    bf16* dV = dK + 16384;
#pragma unroll
    for (int i = 0; i < 4; ++i) {
      int c = i * 512 + t;               // 0..2047
      int row = c >> 4, c16 = c & 15;
      gload_lds16(Kh + (size_t)(kt * 128 + row) * DHn + ((c16 ^ (row & 7)) * 8),
                  dK + c * 8);
    }
#pragma unroll
    for (int i = 0; i < 4; ++i) {
      int c = i * 512 + t;
      int row = c >> 4, c16 = c & 15;    // row = d, c16 = k-chunk
      gload_lds16(VTh + (size_t)row * Sn + kt * 128 + ((c16 ^ (row & 7)) * 8),
                  dV + c * 8);
    }
  };

  const f32x4 zf = {0.f, 0.f, 0.f, 0.f};

  for (int pi = 0; pi < 2; ++pi) {
    const int qb = pi ? (15 - j) : j;    // QBLK=128 block index
    const int nt = qb + 1;               // 128-k tiles
    const int q0 = qb * 128 + wave * 16;
    const int qg = q0 + lr;              // THE q this lane owns

    bf16x8 qf[4];
#pragma unroll
    for (int kk = 0; kk < 4; ++kk)
      qf[kk] = *(const bf16x8*)(Qh + (size_t)(q0 + lr) * DHn + kk * 32 + lg * 8);

    f32x4 o[8];
#pragma unroll
    for (int d = 0; d < 8; ++d) o[d] = zf;
    float mrun = -3e38f, lrun = 0.f;

    // prologue: tile 0 staged and published
    STAGE(0, 0);
    asm volatile("s_waitcnt vmcnt(0)" ::: "memory");
    __builtin_amdgcn_s_barrier();

    for (int kt = 0; kt < nt; ++kt) {
      const int sl = kt & 1;
      if (kt + 1 < nt) STAGE(sl ^ 1, kt + 1);   // depth-1 prefetch

      bf16* sKc = smem + sl * 32768;
      bf16* sVc = sKc + 16384;

      // S^T = K Q^T : sfr[nn] rows = k (nn*16+lg*4+r), cols = q (lr)
      f32x4 sfr[8];
#pragma unroll
      for (int nn = 0; nn < 8; ++nn) sfr[nn] = zf;
#pragma unroll
      for (int kk = 0; kk < 4; ++kk)
#pragma unroll
        for (int nn = 0; nn < 8; ++nn) {
          int row = nn * 16 + lr;
          int ch = (kk * 4 + lg) ^ (row & 7);
          bf16x8 kf = *(const bf16x8*)(sKc + row * 128 + ch * 8);
          sfr[nn] = __builtin_amdgcn_mfma_f32_16x16x32_bf16(kf, qf[kk], sfr[nn], 0, 0, 0);
        }

      // per-lane softmax for q = qg; lane holds k = kt*128 + nn*16 + lg*4 + r
      const bool maskt = (kt == qb);
      float pv[8][4];
#pragma unroll
      for (int nn = 0; nn < 8; ++nn)
#pragma unroll
        for (int r = 0; r < 4; ++r) {
          float v = sfr[nn][r] * (1.0f / 128.0f);
          if (maskt) {
            int kg = kt * 128 + nn * 16 + lg * 4 + r;
            if (kg > qg) v = -1e30f;
          }
          pv[nn][r] = v;
        }
      float rm = -3e38f;
#pragma unroll
      for (int nn = 0; nn < 8; ++nn)
        rm = fmaxf(rm, fmaxf(fmaxf(pv[nn][0], pv[nn][1]), fmaxf(pv[nn][2], pv[nn][3])));
      rm = fmaxf(rm, __shfl_xor(rm, 16));
      rm = fmaxf(rm, __shfl_xor(rm, 32));
      const float mnew = fmaxf(mrun, rm);
      const float alpha = __expf(mrun - mnew);
      float rsum = 0.f;
#pragma unroll
      for (int nn = 0; nn < 8; ++nn)
#pragma unroll
        for (int r = 0; r < 4; ++r) {
          float p = __expf(pv[nn][r] - mnew);
          pv[nn][r] = p;
          rsum += p;
        }
      rsum += __shfl_xor(rsum, 16);
      rsum += __shfl_xor(rsum, 32);
      lrun = lrun * alpha + rsum;
      const bool grew = (mnew > mrun);
      mrun = mnew;
      if (__any(grew)) {
#pragma unroll
        for (int d = 0; d < 8; ++d)
#pragma unroll
          for (int r = 0; r < 4; ++r) o[d][r] *= alpha;
      }

      // PV in two k-halves sharing sP[wave][q=16][k=64]
#pragma unroll
      for (int kh = 0; kh < 2; ++kh) {
        if (kh == 1) {  // prior half's reads must have returned before overwrite
          asm volatile("s_waitcnt lgkmcnt(0)" ::: "memory");
          __builtin_amdgcn_sched_barrier(0);
        }
#pragma unroll
        for (int nn = 0; nn < 4; ++nn)
#pragma unroll
          for (int r = 0; r < 4; ++r) {
            int c = nn * 2 + (lg >> 1);              // local k>>3
            int chk = c ^ (lr & 7);
            sP[wave * 1024 + lr * 64 + chk * 8 + (lg & 1) * 4 + r] =
                __float2bfloat16(pv[kh * 4 + nn][r]);
          }
        bf16x8 pf[2];
#pragma unroll
        for (int kk = 0; kk < 2; ++kk) {
          int ch = (kk * 4 + lg) ^ (lr & 7);
          pf[kk] = *(const bf16x8*)(sP + wave * 1024 + lr * 64 + ch * 8);
        }
#pragma unroll
        for (int d = 0; d < 8; ++d)
#pragma unroll
          for (int kk = 0; kk < 2; ++kk) {
            int vrow = d * 16 + lr;
            int vch = (kh * 8 + kk * 4 + lg) ^ (vrow & 7);
            bf16x8 vf = *(const bf16x8*)(sVc + vrow * 128 + vch * 8);
            o[d] = __builtin_amdgcn_mfma_f32_16x16x32_bf16(vf, pf[kk], o[d], 0, 0, 0);
          }
      }

      // tile end: prefetch must be fully landed before next tile reads it
      asm volatile("s_waitcnt vmcnt(0)" ::: "memory");
      __builtin_amdgcn_s_barrier();
    }

    // epilogue: normalize (scalar), stage to sO[q][d] (swizzled), store
    const float inv = 1.0f / lrun;
#pragma unroll
    for (int d = 0; d < 8; ++d)
#pragma unroll
      for (int r = 0; r < 4; ++r) {
        int row = wave * 16 + lr;                  // q row; row&7 == lr&7
        int col = d * 16 + lg * 4 + r;             // d col
        int chk = (col >> 3) ^ (lr & 7);
        sO[row * 128 + chk * 8 + (col & 7)] = __float2bfloat16(o[d][r] * inv);
      }
    __syncthreads();
    bf16* Mh = Mg + ((size_t)(b * Sn + qb * 128)) * Dn + h * DHn;
#pragma unroll
    for (int i = 0; i < 4; ++i) {
      int row = (t >> 4) + i * 32;
      int c16 = t & 15;
      *(bf16x8*)(Mh + (size_t)row * Dn + c16 * 8) =
          *(const bf16x8*)(sO + row * 128 + ((c16 ^ (row & 7)) * 8));
    }
    __syncthreads();   // sO region is re-staged by next pass
  }
}

// ---------------------------------------------------------------------------
extern "C" void kernel_launch(void* const* d_in, const int* in_sizes, int n_in,
                              void* d_out, int out_size, void* d_ws, size_t ws_size,
                              hipStream_t stream) {
  const float* x = (const float*)d_in[0];
  const float* Wq = (const float*)d_in[1];
  const float* Wk = (const float*)d_in[2];
  const float* Wv = (const float*)d_in[3];
  const float* Wo = (const float*)d_in[4];
  float* out = (float*)d_out;

  char* ws = (char*)d_ws;
  bf16* xb = (bf16*)ws;            ws += (size_t)Mn * Dn * 2;        // 16 MB
  bf16* Wb = (bf16*)ws;            ws += (size_t)4 * Dn * Dn * 2;    // 32 MB (q,k,v,o)
  bf16* QKV = (bf16*)ws;           ws += (size_t)3 * Mn * Dn * 2;    // 48 MB
  bf16* VT = (bf16*)ws;            ws += (size_t)Bn * Hn * DHn * Sn * 2; // 16 MB
  bf16* Mg = (bf16*)ws;            ws += (size_t)Mn * Dn * 2;        // 16 MB

  // all f32->bf16 conversions in one launch
  cvt_all_k<<<dim3(2048, 5), 256, 0, stream>>>(x, Wq, Wk, Wv, Wo, xb, Wb);

  // Q,K,V = x @ W{q,k,v}^T -> bf16 (768 blocks, BM=256)
  gemmY<48, 3><<<768, 256, 0, stream>>>(xb, Wb, QKV);

  // per-head V transpose (plain-view head slabs)
  transpose_v<<<dim3(16, 32), 256, 0, stream>>>(QKV + 2 * (size_t)Mn * Dn, VT);

  // causal attention -> merged [4096, 2048] bf16 (XCD-grouped grid)
  attn_k6<<<256, 512, 0, stream>>>(QKV, QKV + (size_t)Mn * Dn, VT, Mg);

  // out = merged @ Wo^T -> f32 (32 x 8 = 256 blocks = 1/CU, 8 waves)
  gemm8f<8><<<256, 512, 0, stream>>>(Mg, Wb + 3 * (size_t)Dn * Dn, out);
}

// Round 15
// 223.706 us; speedup vs baseline: 1.1919x; 1.0162x over previous
//
#include <hip/hip_runtime.h>
#include <hip/hip_bf16.h>

using bf16 = __hip_bfloat16;
typedef __attribute__((ext_vector_type(8))) short bf16x8;   // 8 bf16 = 4 VGPR
typedef __attribute__((ext_vector_type(4))) float f32x4;    // MFMA C/D frag

#define DEVI __device__ __forceinline__

constexpr int Bn = 2, Sn = 2048, Dn = 2048, Hn = 16, DHn = 128;
constexpr int Mn = Bn * Sn;   // 4096

DEVI void gload_lds16(const bf16* g, bf16* l) {
  __builtin_amdgcn_global_load_lds(
      (__attribute__((address_space(1))) void*)g,
      (__attribute__((address_space(3))) void*)l,
      16, 0, 0);
}

// ---------------- fused f32 -> bf16 convert (x + 4 weights, one launch) ----
__global__ __launch_bounds__(256) void cvt_all_k(const float* __restrict__ x,
                                                 const float* __restrict__ wq,
                                                 const float* __restrict__ wk,
                                                 const float* __restrict__ wv,
                                                 const float* __restrict__ wo,
                                                 bf16* __restrict__ xb,
                                                 bf16* __restrict__ wb) {
  const int which = blockIdx.y;
  const float* src;
  bf16* dst;
  int n8;
  if (which == 0) { src = x;  dst = xb; n8 = Mn * Dn / 8; }
  else {
    src = (which == 1) ? wq : (which == 2) ? wk : (which == 3) ? wv : wo;
    dst = wb + (size_t)(which - 1) * Dn * Dn;
    n8 = Dn * Dn / 8;
  }
  for (int i = blockIdx.x * 256 + threadIdx.x; i < n8; i += gridDim.x * 256) {
    const float4* p = (const float4*)src + (size_t)i * 2;
    float4 a = p[0], b = p[1];
    union { bf16 h[8]; bf16x8 v; } u;
    u.h[0] = __float2bfloat16(a.x); u.h[1] = __float2bfloat16(a.y);
    u.h[2] = __float2bfloat16(a.z); u.h[3] = __float2bfloat16(a.w);
    u.h[4] = __float2bfloat16(b.x); u.h[5] = __float2bfloat16(b.y);
    u.h[6] = __float2bfloat16(b.z); u.h[7] = __float2bfloat16(b.w);
    *((bf16x8*)dst + i) = u.v;
  }
}

// ---------------- GEMM 256: C = A[M,K] * W[N,K]^T  (m201-geometry) ---------
// BM=BN=256, BK=64, 512 thr = 8 waves (2M x 4N), per-wave C = 128x64
// (acc[8][4]). 2-slot LDS ring (128 KB, 1 block/CU). 4 quadrant phases per
// K-tile, 16 MFMA each; 2 barriers/K-tile; counted vmcnt (never 0 in loop).
// Staging units: 8 x 8KB per K-tile (A0..A3 rows u*64.., B0..B3), issue
// order per tile = [A0,A2,B0,B1,B2,B3,A1,A3] (prologue AND in-loop).
// Per-wave FIFO ledger (steady state):
//   tile top: outstanding = this tile's [A1,A3]  -> vmcnt(2) lands first 6
//             (A0,A2,B0..B3 needed by p0/p1); s_barrier publishes them.
//   p0: read af0(8)+bv01(4); stage next A0,A2,B0,B1; lgkm0; 16 MFMA (m0,n01)
//   p1: read bv23(4);        stage next B2,B3;       lgkm0; 16 MFMA (m0,n23)
//   p2: vmcnt(6) (+0 on last tile) retires this tile's A1,A3; s_barrier
//       publishes them; read af1(8); stage next A1,A3; lgkm0; 16 MFMA (m1,n23)
//   p3: reg-only; 16 MFMA (m1,n01)
// Slot safety: next tile -> slot^1, whose last readers (tile kt-1) drained
// (lgkm0 before their MFMAs) before crossing this tile's top barrier.
template <int NCT, int NMAT>
__global__ __launch_bounds__(512, 1) void gemm256(const bf16* __restrict__ A,
                                                  const bf16* __restrict__ W,
                                                  bf16* __restrict__ Cv) {
  constexpr int K = 2048, NT = K / 64;   // 32 K-tiles
  constexpr int SLOT = 32768;            // elems: A[256][64] + B[256][64]
  __shared__ bf16 smem[2 * SLOT];        // 128 KB

  constexpr int MT = Mn / 256;           // 16
  const int nwg = MT * NCT;
  const int orig = blockIdx.x;
  const int wgid = (orig & 7) * (nwg >> 3) + (orig >> 3);   // XCD swizzle (nwg%8==0)
  const int bm = wgid / NCT;
  const int bcn = wgid % NCT;
  constexpr int nper = NCT / NMAT;
  const int z = bcn / nper;
  const int col0 = (bcn % nper) * 256;

  const int t = threadIdx.x;
  const int wave = t >> 6, lane = t & 63;
  const int wm = wave >> 2, wn = wave & 3;
  const int lr = lane & 15, lg = lane >> 4;

  const int srow = t >> 3;                       // staging row within unit
  const int schk = (t & 7) ^ (srow & 7);         // pre-swizzled src chunk
  const bf16* Ab = A + (size_t)(bm * 256 + srow) * K + schk * 8;
  const bf16* Bb = W + (size_t)z * (2048 * 2048) +
                   (size_t)(col0 + srow) * K + schk * 8;

  auto stgA = [&](int slot, int kt, int u) {
    gload_lds16(Ab + (size_t)u * 64 * K + kt * 64,
                smem + slot * SLOT + u * 4096 + t * 8);
  };
  auto stgB = [&](int slot, int kt, int u) {
    gload_lds16(Bb + (size_t)u * 64 * K + kt * 64,
                smem + slot * SLOT + 16384 + u * 4096 + t * 8);
  };

  f32x4 acc[8][4];
  const f32x4 zf = {0.f, 0.f, 0.f, 0.f};
#pragma unroll
  for (int i = 0; i < 8; ++i)
#pragma unroll
    for (int j = 0; j < 4; ++j) acc[i][j] = zf;

  // prologue: tile 0, canonical issue order
  stgA(0, 0, 0); stgA(0, 0, 2);
  stgB(0, 0, 0); stgB(0, 0, 1); stgB(0, 0, 2); stgB(0, 0, 3);
  stgA(0, 0, 1); stgA(0, 0, 3);

#pragma unroll 2
  for (int kt = 0; kt < NT; ++kt) {
    const int sl = kt & 1;
    const bf16* sA = smem + sl * SLOT;
    const bf16* sB = sA + 16384;
    const bool pf = (kt + 1 < NT);

    // ---- tile top: first 6 units of tile kt landed; publish ----
    asm volatile("s_waitcnt vmcnt(2)" ::: "memory");
    __builtin_amdgcn_s_barrier();

    bf16x8 af[4][2], bv0[2][2], bv1[2][2];

    // ---- p0: quadrant (m0, n01) ----
#pragma unroll
    for (int i = 0; i < 4; ++i)
#pragma unroll
      for (int kk = 0; kk < 2; ++kk) {
        int row = wm * 128 + i * 16 + lr;
        af[i][kk] = *(const bf16x8*)(sA + row * 64 + (((kk * 4 + lg) ^ (row & 7)) * 8));
      }
#pragma unroll
    for (int n = 0; n < 2; ++n)
#pragma unroll
      for (int kk = 0; kk < 2; ++kk) {
        int row = wn * 64 + n * 16 + lr;
        bv0[n][kk] = *(const bf16x8*)(sB + row * 64 + (((kk * 4 + lg) ^ (row & 7)) * 8));
      }
    if (pf) { stgA(sl ^ 1, kt + 1, 0); stgA(sl ^ 1, kt + 1, 2);
              stgB(sl ^ 1, kt + 1, 0); stgB(sl ^ 1, kt + 1, 1); }
    asm volatile("s_waitcnt lgkmcnt(0)" ::: "memory");
    __builtin_amdgcn_sched_barrier(0);
    __builtin_amdgcn_s_setprio(1);
#pragma unroll
    for (int kk = 0; kk < 2; ++kk)
#pragma unroll
      for (int i = 0; i < 4; ++i)
#pragma unroll
        for (int n = 0; n < 2; ++n)
          acc[i][n] = __builtin_amdgcn_mfma_f32_16x16x32_bf16(af[i][kk], bv0[n][kk], acc[i][n], 0, 0, 0);
    __builtin_amdgcn_s_setprio(0);

    // ---- p1: quadrant (m0, n23) ----
#pragma unroll
    for (int n = 0; n < 2; ++n)
#pragma unroll
      for (int kk = 0; kk < 2; ++kk) {
        int row = wn * 64 + 32 + n * 16 + lr;
        bv1[n][kk] = *(const bf16x8*)(sB + row * 64 + (((kk * 4 + lg) ^ (row & 7)) * 8));
      }
    if (pf) { stgB(sl ^ 1, kt + 1, 2); stgB(sl ^ 1, kt + 1, 3); }
    asm volatile("s_waitcnt lgkmcnt(0)" ::: "memory");
    __builtin_amdgcn_sched_barrier(0);
    __builtin_amdgcn_s_setprio(1);
#pragma unroll
    for (int kk = 0; kk < 2; ++kk)
#pragma unroll
      for (int i = 0; i < 4; ++i)
#pragma unroll
        for (int n = 0; n < 2; ++n)
          acc[i][2 + n] = __builtin_amdgcn_mfma_f32_16x16x32_bf16(af[i][kk], bv1[n][kk], acc[i][2 + n], 0, 0, 0);
    __builtin_amdgcn_s_setprio(0);

    // ---- p2: publish this tile's A1,A3; quadrant (m1, n23) ----
    if (pf) asm volatile("s_waitcnt vmcnt(6)" ::: "memory");
    else    asm volatile("s_waitcnt vmcnt(0)" ::: "memory");
    __builtin_amdgcn_s_barrier();
#pragma unroll
    for (int i = 0; i < 4; ++i)
#pragma unroll
      for (int kk = 0; kk < 2; ++kk) {
        int row = wm * 128 + 64 + i * 16 + lr;
        af[i][kk] = *(const bf16x8*)(sA + row * 64 + (((kk * 4 + lg) ^ (row & 7)) * 8));
      }
    if (pf) { stgA(sl ^ 1, kt + 1, 1); stgA(sl ^ 1, kt + 1, 3); }
    asm volatile("s_waitcnt lgkmcnt(0)" ::: "memory");
    __builtin_amdgcn_sched_barrier(0);
    __builtin_amdgcn_s_setprio(1);
#pragma unroll
    for (int kk = 0; kk < 2; ++kk)
#pragma unroll
      for (int i = 0; i < 4; ++i)
#pragma unroll
        for (int n = 0; n < 2; ++n)
          acc[4 + i][2 + n] = __builtin_amdgcn_mfma_f32_16x16x32_bf16(af[i][kk], bv1[n][kk], acc[4 + i][2 + n], 0, 0, 0);
    __builtin_amdgcn_s_setprio(0);

    // ---- p3: quadrant (m1, n01), register-only ----
    __builtin_amdgcn_s_setprio(1);
#pragma unroll
    for (int kk = 0; kk < 2; ++kk)
#pragma unroll
      for (int i = 0; i < 4; ++i)
#pragma unroll
        for (int n = 0; n < 2; ++n)
          acc[4 + i][n] = __builtin_amdgcn_mfma_f32_16x16x32_bf16(af[i][kk], bv0[n][kk], acc[4 + i][n], 0, 0, 0);
    __builtin_amdgcn_s_setprio(0);
    __builtin_amdgcn_sched_barrier(0);
  }

  // epilogue (bf16 out, z-slab)
  const int r0 = bm * 256 + wm * 128, c0 = col0 + wn * 64;
#pragma unroll
  for (int mm = 0; mm < 8; ++mm)
#pragma unroll
    for (int nn = 0; nn < 4; ++nn) {
      const int rr = r0 + mm * 16 + lg * 4;
      const int cc = c0 + nn * 16 + lr;
      bf16* C = Cv + (size_t)z * (Mn * 2048);
#pragma unroll
      for (int r = 0; r < 4; ++r)
        C[(size_t)(rr + r) * 2048 + cc] = __float2bfloat16(acc[mm][nn][r]);
    }
}

// ---------------- GEMM 8F (out-proj): fine-phase, BM=128 BN=256 ------------
template <int NCT>
__global__ __launch_bounds__(512, 1) void gemm8f(const bf16* __restrict__ A,
                                                 const bf16* __restrict__ W,
                                                 float* __restrict__ Cv) {
  constexpr int K = 2048, NT = K / 64;            // 32 K-tiles
  constexpr int SLOTE = (128 + 256) * 64;         // 24576 elems per slot
  __shared__ bf16 smem[3 * SLOTE];                // 147456 B

  constexpr int MT = Mn / 128;                    // 32 row tiles
  const int nwg = MT * NCT;
  const int orig = blockIdx.x;
  const int wgid = (orig & 7) * (nwg >> 3) + (orig >> 3);   // XCD swizzle
  const int bm = wgid / NCT;
  const int bcn = wgid % NCT;
  const int col0 = bcn * 256;

  const int t = threadIdx.x;
  const int wave = t >> 6, lane = t & 63;
  const int wm = wave >> 2, wn = wave & 3;
  const int lr = lane & 15, lg = lane >> 4;
  const int swz = lr & 7;

  const int srow = t >> 3;
  const int schk = (t & 7) ^ (srow & 7);
  const bf16* Ab = A + (size_t)(bm * 128 + srow) * K + schk * 8;
  const bf16* Bb = W + (size_t)(col0 + srow) * K + schk * 8;

  auto stgA = [&](int slot, int kt, int u) {
    gload_lds16(Ab + (size_t)u * 64 * K + kt * 64,
                smem + slot * SLOTE + u * 4096 + t * 8);
  };
  auto stgB = [&](int slot, int kt, int u) {
    gload_lds16(Bb + (size_t)u * 64 * K + kt * 64,
                smem + slot * SLOTE + 8192 + u * 4096 + t * 8);
  };

  f32x4 acc[4][4];
  const f32x4 zf = {0.f, 0.f, 0.f, 0.f};
#pragma unroll
  for (int i = 0; i < 4; ++i)
#pragma unroll
    for (int j = 0; j < 4; ++j) acc[i][j] = zf;

  stgA(0, 0, 0); stgA(0, 0, 1);
  stgB(0, 0, 0); stgB(0, 0, 1); stgB(0, 0, 2); stgB(0, 0, 3);
  stgA(1, 1, 0); stgA(1, 1, 1);
  stgB(1, 1, 0); stgB(1, 1, 1); stgB(1, 1, 2); stgB(1, 1, 3);

  int sl = 0;
#pragma unroll 1
  for (int kt = 0; kt < NT; ++kt) {
    const bf16* sA = smem + sl * SLOTE;
    const bf16* sB = sA + 8192;
    int sl2 = sl + 2; if (sl2 >= 3) sl2 -= 3;
    const bool pf = (kt + 2 < NT);

    if (kt == NT - 1) asm volatile("s_waitcnt vmcnt(0)" ::: "memory");
    else              asm volatile("s_waitcnt vmcnt(6)" ::: "memory");
    __builtin_amdgcn_s_barrier();

    {
      bf16x8 af[4], bv[4];
#pragma unroll
      for (int i = 0; i < 4; ++i)
        af[i] = *(const bf16x8*)(sA + (wm * 64 + i * 16 + lr) * 64 + ((lg ^ swz) * 8));
#pragma unroll
      for (int n = 0; n < 4; ++n)
        bv[n] = *(const bf16x8*)(sB + (wn * 64 + n * 16 + lr) * 64 + ((lg ^ swz) * 8));
      if (pf) { stgA(sl2, kt + 2, 0); stgA(sl2, kt + 2, 1); stgB(sl2, kt + 2, 0); }
      __builtin_amdgcn_s_barrier();
      asm volatile("s_waitcnt lgkmcnt(0)" ::: "memory");
      __builtin_amdgcn_sched_barrier(0);
      __builtin_amdgcn_s_setprio(1);
#pragma unroll
      for (int i = 0; i < 4; ++i)
#pragma unroll
        for (int n = 0; n < 4; ++n)
          acc[i][n] = __builtin_amdgcn_mfma_f32_16x16x32_bf16(af[i], bv[n], acc[i][n], 0, 0, 0);
      __builtin_amdgcn_s_setprio(0);
      __builtin_amdgcn_s_barrier();
    }
    {
      bf16x8 af[4], bv[4];
#pragma unroll
      for (int i = 0; i < 4; ++i)
        af[i] = *(const bf16x8*)(sA + (wm * 64 + i * 16 + lr) * 64 + (((4 + lg) ^ swz) * 8));
#pragma unroll
      for (int n = 0; n < 4; ++n)
        bv[n] = *(const bf16x8*)(sB + (wn * 64 + n * 16 + lr) * 64 + (((4 + lg) ^ swz) * 8));
      if (pf) { stgB(sl2, kt + 2, 1); stgB(sl2, kt + 2, 2); stgB(sl2, kt + 2, 3); }
      __builtin_amdgcn_s_barrier();
      asm volatile("s_waitcnt lgkmcnt(0)" ::: "memory");
      __builtin_amdgcn_sched_barrier(0);
      __builtin_amdgcn_s_setprio(1);
#pragma unroll
      for (int i = 0; i < 4; ++i)
#pragma unroll
        for (int n = 0; n < 4; ++n)
          acc[i][n] = __builtin_amdgcn_mfma_f32_16x16x32_bf16(af[i], bv[n], acc[i][n], 0, 0, 0);
      __builtin_amdgcn_s_setprio(0);
    }
    sl = (sl == 2) ? 0 : sl + 1;
  }

  const int r0 = bm * 128 + wm * 64, c0 = col0 + wn * 64;
#pragma unroll
  for (int mm = 0; mm < 4; ++mm)
#pragma unroll
    for (int nn = 0; nn < 4; ++nn) {
      const int rr = r0 + mm * 16 + lg * 4;
      const int cc = c0 + nn * 16 + lr;
#pragma unroll
      for (int r = 0; r < 4; ++r)
        Cv[(size_t)(rr + r) * 2048 + cc] = acc[mm][nn][r];
    }
}

// ---------------- V transpose: per (b,h)  V[2048,128] -> VT[128,2048] ------
__global__ __launch_bounds__(256, 2) void transpose_v(const bf16* __restrict__ V,
                                                      bf16* __restrict__ VT) {
  __shared__ bf16 tile[128 * 128];   // 32 KB, chunk-XOR-swizzled
  const int kt = blockIdx.x, bh = blockIdx.y;
  const bf16* Vh = V + (size_t)bh * (Sn * DHn);
  bf16* VTh = VT + (size_t)bh * (DHn * Sn);
  const int t = threadIdx.x;
  const int rr = t >> 4, cc = t & 15;
#pragma unroll
  for (int i = 0; i < 8; ++i) {
    int r = rr + i * 16;
    int ch = cc ^ ((r >> 3) & 7);
    *(bf16x8*)(tile + r * 128 + ch * 8) =
        *(const bf16x8*)(Vh + (size_t)(kt * 128 + r) * DHn + cc * 8);
  }
  __syncthreads();
  const int dr = t >> 4, li = t & 15;
#pragma unroll
  for (int i = 0; i < 8; ++i) {
    int dh = dr + i * 16;
    union { bf16 h[8]; bf16x8 v; } u;
#pragma unroll
    for (int j = 0; j < 8; ++j) {
      int k = li * 8 + j;
      int ch = (dh >> 3) ^ ((k >> 3) & 7);
      u.h[j] = tile[k * 128 + ch * 8 + (dh & 7)];
    }
    *(bf16x8*)(VTh + (size_t)dh * Sn + kt * 128 + li * 8) = u.v;
  }
}

// ---------------- causal flash attention v6 (KBLK=128) ---------------------
__global__ __launch_bounds__(512, 1) void attn_k6(const bf16* __restrict__ Q,
                                                  const bf16* __restrict__ K,
                                                  const bf16* __restrict__ VT,
                                                  bf16* __restrict__ Mg) {
  __shared__ bf16 smem[73728];         // 144 KB: 2 x (sK 32KB + sV 32KB) + sP 16KB
  bf16* sP = smem + 65536;             // 8 waves x [q=16][k=64] swizzled
  bf16* sO = smem;                     // epilogue reuse [128][128] (32 KB)

  const int bi = blockIdx.x;           // XCD-grouped decode
  const int xcd = bi & 7, slt = bi >> 3;
  const int bh = (slt & 3) * 8 + xcd;  // 4 bh per XCD -> K/V L2-resident
  const int j = slt >> 2;              // pair index 0..7
  const bf16* Qh = Q + (size_t)bh * (Sn * DHn);
  const bf16* Kh = K + (size_t)bh * (Sn * DHn);
  const bf16* VTh = VT + (size_t)bh * (DHn * Sn);
  const int b = bh >> 4, h = bh & 15;

  const int t = threadIdx.x, wave = t >> 6, lane = t & 63;
  const int lr = lane & 15, lg = lane >> 4;

  auto STAGE = [&](int s, int kt) {
    bf16* dK = smem + s * 32768;
    bf16* dV = dK + 16384;
#pragma unroll
    for (int i = 0; i < 4; ++i) {
      int c = i * 512 + t;               // 0..2047
      int row = c >> 4, c16 = c & 15;
      gload_lds16(Kh + (size_t)(kt * 128 + row) * DHn + ((c16 ^ (row & 7)) * 8),
                  dK + c * 8);
    }
#pragma unroll
    for (int i = 0; i < 4; ++i) {
      int c = i * 512 + t;
      int row = c >> 4, c16 = c & 15;    // row = d, c16 = k-chunk
      gload_lds16(VTh + (size_t)row * Sn + kt * 128 + ((c16 ^ (row & 7)) * 8),
                  dV + c * 8);
    }
  };

  const f32x4 zf = {0.f, 0.f, 0.f, 0.f};

  for (int pi = 0; pi < 2; ++pi) {
    const int qb = pi ? (15 - j) : j;    // QBLK=128 block index
    const int nt = qb + 1;               // 128-k tiles
    const int q0 = qb * 128 + wave * 16;
    const int qg = q0 + lr;              // THE q this lane owns

    bf16x8 qf[4];
#pragma unroll
    for (int kk = 0; kk < 4; ++kk)
      qf[kk] = *(const bf16x8*)(Qh + (size_t)(q0 + lr) * DHn + kk * 32 + lg * 8);

    f32x4 o[8];
#pragma unroll
    for (int d = 0; d < 8; ++d) o[d] = zf;
    float mrun = -3e38f, lrun = 0.f;

    STAGE(0, 0);
    asm volatile("s_waitcnt vmcnt(0)" ::: "memory");
    __builtin_amdgcn_s_barrier();

    for (int kt = 0; kt < nt; ++kt) {
      const int sl = kt & 1;
      if (kt + 1 < nt) STAGE(sl ^ 1, kt + 1);   // depth-1 prefetch

      bf16* sKc = smem + sl * 32768;
      bf16* sVc = sKc + 16384;

      // S^T = K Q^T : sfr[nn] rows = k (nn*16+lg*4+r), cols = q (lr)
      f32x4 sfr[8];
#pragma unroll
      for (int nn = 0; nn < 8; ++nn) sfr[nn] = zf;
#pragma unroll
      for (int kk = 0; kk < 4; ++kk)
#pragma unroll
        for (int nn = 0; nn < 8; ++nn) {
          int row = nn * 16 + lr;
          int ch = (kk * 4 + lg) ^ (row & 7);
          bf16x8 kf = *(const bf16x8*)(sKc + row * 128 + ch * 8);
          sfr[nn] = __builtin_amdgcn_mfma_f32_16x16x32_bf16(kf, qf[kk], sfr[nn], 0, 0, 0);
        }

      const bool maskt = (kt == qb);
      float pv[8][4];
#pragma unroll
      for (int nn = 0; nn < 8; ++nn)
#pragma unroll
        for (int r = 0; r < 4; ++r) {
          float v = sfr[nn][r] * (1.0f / 128.0f);
          if (maskt) {
            int kg = kt * 128 + nn * 16 + lg * 4 + r;
            if (kg > qg) v = -1e30f;
          }
          pv[nn][r] = v;
        }
      float rm = -3e38f;
#pragma unroll
      for (int nn = 0; nn < 8; ++nn)
        rm = fmaxf(rm, fmaxf(fmaxf(pv[nn][0], pv[nn][1]), fmaxf(pv[nn][2], pv[nn][3])));
      rm = fmaxf(rm, __shfl_xor(rm, 16));
      rm = fmaxf(rm, __shfl_xor(rm, 32));
      const float mnew = fmaxf(mrun, rm);
      const float alpha = __expf(mrun - mnew);
      float rsum = 0.f;
#pragma unroll
      for (int nn = 0; nn < 8; ++nn)
#pragma unroll
        for (int r = 0; r < 4; ++r) {
          float p = __expf(pv[nn][r] - mnew);
          pv[nn][r] = p;
          rsum += p;
        }
      rsum += __shfl_xor(rsum, 16);
      rsum += __shfl_xor(rsum, 32);
      lrun = lrun * alpha + rsum;
      const bool grew = (mnew > mrun);
      mrun = mnew;
      if (__any(grew)) {
#pragma unroll
        for (int d = 0; d < 8; ++d)
#pragma unroll
          for (int r = 0; r < 4; ++r) o[d][r] *= alpha;
      }

      // PV in two k-halves sharing sP[wave][q=16][k=64]
#pragma unroll
      for (int kh = 0; kh < 2; ++kh) {
        if (kh == 1) {
          asm volatile("s_waitcnt lgkmcnt(0)" ::: "memory");
          __builtin_amdgcn_sched_barrier(0);
        }
#pragma unroll
        for (int nn = 0; nn < 4; ++nn)
#pragma unroll
          for (int r = 0; r < 4; ++r) {
            int c = nn * 2 + (lg >> 1);              // local k>>3
            int chk = c ^ (lr & 7);
            sP[wave * 1024 + lr * 64 + chk * 8 + (lg & 1) * 4 + r] =
                __float2bfloat16(pv[kh * 4 + nn][r]);
          }
        bf16x8 pf[2];
#pragma unroll
        for (int kk = 0; kk < 2; ++kk) {
          int ch = (kk * 4 + lg) ^ (lr & 7);
          pf[kk] = *(const bf16x8*)(sP + wave * 1024 + lr * 64 + ch * 8);
        }
#pragma unroll
        for (int d = 0; d < 8; ++d)
#pragma unroll
          for (int kk = 0; kk < 2; ++kk) {
            int vrow = d * 16 + lr;
            int vch = (kh * 8 + kk * 4 + lg) ^ (vrow & 7);
            bf16x8 vf = *(const bf16x8*)(sVc + vrow * 128 + vch * 8);
            o[d] = __builtin_amdgcn_mfma_f32_16x16x32_bf16(vf, pf[kk], o[d], 0, 0, 0);
          }
      }

      asm volatile("s_waitcnt vmcnt(0)" ::: "memory");
      __builtin_amdgcn_s_barrier();
    }

    const float inv = 1.0f / lrun;
#pragma unroll
    for (int d = 0; d < 8; ++d)
#pragma unroll
      for (int r = 0; r < 4; ++r) {
        int row = wave * 16 + lr;
        int col = d * 16 + lg * 4 + r;
        int chk = (col >> 3) ^ (lr & 7);
        sO[row * 128 + chk * 8 + (col & 7)] = __float2bfloat16(o[d][r] * inv);
      }
    __syncthreads();
    bf16* Mh = Mg + ((size_t)(b * Sn + qb * 128)) * Dn + h * DHn;
#pragma unroll
    for (int i = 0; i < 4; ++i) {
      int row = (t >> 4) + i * 32;
      int c16 = t & 15;
      *(bf16x8*)(Mh + (size_t)row * Dn + c16 * 8) =
          *(const bf16x8*)(sO + row * 128 + ((c16 ^ (row & 7)) * 8));
    }
    __syncthreads();
  }
}

// ---------------------------------------------------------------------------
extern "C" void kernel_launch(void* const* d_in, const int* in_sizes, int n_in,
                              void* d_out, int out_size, void* d_ws, size_t ws_size,
                              hipStream_t stream) {
  const float* x = (const float*)d_in[0];
  const float* Wq = (const float*)d_in[1];
  const float* Wk = (const float*)d_in[2];
  const float* Wv = (const float*)d_in[3];
  const float* Wo = (const float*)d_in[4];
  float* out = (float*)d_out;

  char* ws = (char*)d_ws;
  bf16* xb = (bf16*)ws;            ws += (size_t)Mn * Dn * 2;        // 16 MB
  bf16* Wb = (bf16*)ws;            ws += (size_t)4 * Dn * Dn * 2;    // 32 MB (q,k,v,o)
  bf16* QKV = (bf16*)ws;           ws += (size_t)3 * Mn * Dn * 2;    // 48 MB
  bf16* VT = (bf16*)ws;            ws += (size_t)Bn * Hn * DHn * Sn * 2; // 16 MB
  bf16* Mg = (bf16*)ws;            ws += (size_t)Mn * Dn * 2;        // 16 MB

  // all f32->bf16 conversions in one launch
  cvt_all_k<<<dim3(2048, 5), 256, 0, stream>>>(x, Wq, Wk, Wv, Wo, xb, Wb);

  // Q,K,V = x @ W{q,k,v}^T -> bf16 (16 x 24 = 384 blocks, 256^2 tile)
  gemm256<24, 3><<<384, 512, 0, stream>>>(xb, Wb, QKV);

  // per-head V transpose (plain-view head slabs)
  transpose_v<<<dim3(16, 32), 256, 0, stream>>>(QKV + 2 * (size_t)Mn * Dn, VT);

  // causal attention -> merged [4096, 2048] bf16 (XCD-grouped grid)
  attn_k6<<<256, 512, 0, stream>>>(QKV, QKV + (size_t)Mn * Dn, VT, Mg);

  // out = merged @ Wo^T -> f32 (32 x 8 = 256 blocks = 1/CU, 8 waves)
  gemm8f<8><<<256, 512, 0, stream>>>(Mg, Wb + 3 * (size_t)Dn * Dn, out);
}